// Round 2
// baseline (2315.038 us; speedup 1.0000x reference)
//
#include <hip/hip_runtime.h>
#include <float.h>

#define N_TRAIN 50000
#define DDIM    384
#define M_ROWS  1568   // 8*196
#define KNN     20
#define K2      24     // per-chunk candidates (margin over 20)
#define NCLS    21
#define CHUNK   8192
#define NCHUNKS 7      // 7*8192 = 57344 >= 50000
#define NCAND   (NCHUNKS * K2)   // 168
#define BM      16
#define BN      1024   // 256 threads * 4 cols

// ---------------- transpose labels [256][50000] i32 -> [50000][256] u8 --------
__global__ __launch_bounds__(256) void transpose_labels(const int* __restrict__ labels,
                                                        unsigned char* __restrict__ labT) {
  __shared__ int tile[64][65];
  const int t  = threadIdx.x;
  const int c0 = blockIdx.x * 64;
  const int r0 = blockIdx.y * 64;
#pragma unroll
  for (int i = 0; i < 16; ++i) {
    int idx = i * 256 + t;
    int r = idx >> 6, c = idx & 63;
    int cc = c0 + c;
    tile[r][c] = (cc < N_TRAIN) ? labels[(size_t)(r0 + r) * N_TRAIN + cc] : 0;
  }
  __syncthreads();
#pragma unroll
  for (int i = 0; i < 16; ++i) {
    int idx = i * 256 + t;
    int c = idx >> 6, r = idx & 63;
    int cc = c0 + c;
    if (cc < N_TRAIN) labT[(size_t)cc * 256 + r0 + r] = (unsigned char)tile[r][c];
  }
}

// ---------------- GEMM chunk: sim[m][lc] = dot(test[m], train[:, gc]) ---------
#define FMA4(rr, av) { acc[rr].x = fmaf((av), b.x, acc[rr].x); \
                       acc[rr].y = fmaf((av), b.y, acc[rr].y); \
                       acc[rr].z = fmaf((av), b.z, acc[rr].z); \
                       acc[rr].w = fmaf((av), b.w, acc[rr].w); }

__global__ __launch_bounds__(256) void gemm_chunk(const float* __restrict__ test,
                                                  const float* __restrict__ train,
                                                  float* __restrict__ simbuf, int ch) {
  const int t  = threadIdx.x;
  const int m0 = blockIdx.x * BM;          // row block (98)
  const int lc = blockIdx.y * BN + t * 4;  // local col in chunk
  const int gc = ch * CHUNK + lc;          // global col
  const bool valid = gc < N_TRAIN;         // gc,N both multiples of 4 -> no straddle
  const int gcc = valid ? gc : (N_TRAIN - 4);
  const float* Bb = train + gcc;

  float4 acc[16];
#pragma unroll
  for (int r = 0; r < 16; ++r) acc[r] = make_float4(0.f, 0.f, 0.f, 0.f);

  for (int d = 0; d < DDIM; d += 4) {
    float4 av[16];
#pragma unroll
    for (int r = 0; r < 16; ++r)
      av[r] = *(const float4*)&test[(size_t)(m0 + r) * DDIM + d];  // block-uniform
#pragma unroll
    for (int dd = 0; dd < 4; ++dd) {
      float4 b = *(const float4*)(Bb + (size_t)(d + dd) * N_TRAIN);
#pragma unroll
      for (int r = 0; r < 16; ++r) {
        float ar = (dd == 0) ? av[r].x : (dd == 1) ? av[r].y : (dd == 2) ? av[r].z : av[r].w;
        FMA4(r, ar)
      }
    }
  }

#pragma unroll
  for (int r = 0; r < 16; ++r) {
    float4 o = valid ? acc[r] : make_float4(-FLT_MAX, -FLT_MAX, -FLT_MAX, -FLT_MAX);
    *(float4*)&simbuf[(size_t)(m0 + r) * CHUNK + lc] = o;
  }
}

// ---------------- per-(row,chunk) exact top-K2 extraction ---------------------
__global__ __launch_bounds__(256) void select_chunk(const float* __restrict__ simbuf,
                                                    float* __restrict__ topv,
                                                    int* __restrict__ topi, int ch) {
  const int t = threadIdx.x;
  const int m = blockIdx.x;
  float v[32];
#pragma unroll
  for (int i = 0; i < 32; ++i) v[i] = simbuf[(size_t)m * CHUNK + i * 256 + t];
  float mv = v[0]; int ms = 0;
#pragma unroll
  for (int i = 1; i < 32; ++i) if (v[i] > mv) { mv = v[i]; ms = i; }

  __shared__ float swv[4];
  __shared__ int   swj[4];

  for (int k = 0; k < K2; ++k) {
    float rv = mv; int rj = ms * 256 + t;   // chunk-local col index
#pragma unroll
    for (int off = 32; off > 0; off >>= 1) {
      float ov = __shfl_xor(rv, off);
      int   oj = __shfl_xor(rj, off);
      if (ov > rv || (ov == rv && oj < rj)) { rv = ov; rj = oj; }
    }
    if ((t & 63) == 0) { swv[t >> 6] = rv; swj[t >> 6] = rj; }
    __syncthreads();
    float wv = swv[0]; int wj = swj[0];
#pragma unroll
    for (int w = 1; w < 4; ++w)
      if (swv[w] > wv || (swv[w] == wv && swj[w] < wj)) { wv = swv[w]; wj = swj[w]; }
    __syncthreads();   // protect swv/swj reuse next iteration
    if (t == (wj & 255)) {
      int slot = wj >> 8;
#pragma unroll
      for (int i = 0; i < 32; ++i) if (i == slot) v[i] = -FLT_MAX;
      mv = v[0]; ms = 0;
#pragma unroll
      for (int i = 1; i < 32; ++i) if (v[i] > mv) { mv = v[i]; ms = i; }
    }
    if (t == 0) {
      topv[(size_t)m * NCAND + ch * K2 + k] = wv;
      topi[(size_t)m * NCAND + ch * K2 + k] = ch * CHUNK + wj;
    }
  }
}

// ---------------- merge 168 -> 24 cand, f64 refine, top-20, f64 softmax -------
__global__ __launch_bounds__(64) void merge_refine(const float* __restrict__ topv,
                                                   const int* __restrict__ topi,
                                                   const float* __restrict__ test,
                                                   const float* __restrict__ train,
                                                   double* __restrict__ wval,
                                                   int* __restrict__ widx) {
  const int m = blockIdx.x;
  const int lane = threadIdx.x;   // 64

  // f32 merge to top-24 candidates (uniform across lanes)
  float lv[K2]; int li[K2];
#pragma unroll
  for (int j = 0; j < K2; ++j) { lv[j] = -FLT_MAX; li[j] = -1; }
  for (int n = 0; n < NCAND; ++n) {
    float nv = topv[(size_t)m * NCAND + n];
    int   ni = topi[(size_t)m * NCAND + n];
    if (nv <= lv[K2 - 1]) continue;
#pragma unroll
    for (int j = 0; j < K2; ++j) {
      bool sw = nv > lv[j];
      float tv = lv[j]; int ti = li[j];
      if (sw) { lv[j] = nv; li[j] = ni; nv = tv; ni = ti; }
    }
  }

  // f64 recompute of the 24 candidate sims (wave-parallel over d)
  double rv[K2];
#pragma unroll
  for (int c = 0; c < K2; ++c) {
    const int col = li[c];
    double s = 0.0;
#pragma unroll
    for (int dd = 0; dd < DDIM / 64; ++dd) {
      int d = dd * 64 + lane;
      s += (double)test[(size_t)m * DDIM + d] * (double)train[(size_t)d * N_TRAIN + col];
    }
#pragma unroll
    for (int off = 32; off > 0; off >>= 1) s += __shfl_xor(s, off);
    rv[c] = s;   // all lanes hold the full sum (butterfly)
  }

  // select top-20 by (f64 value desc, idx asc)
  bool used[K2];
#pragma unroll
  for (int c = 0; c < K2; ++c) used[c] = false;
  double sv[KNN]; int si[KNN];
  for (int k = 0; k < KNN; ++k) {
    int best = -1;
#pragma unroll
    for (int c = 0; c < K2; ++c) {
      if (used[c]) continue;
      if (best < 0 || rv[c] > rv[best] || (rv[c] == rv[best] && li[c] < li[best])) best = c;
    }
    used[best] = true; sv[k] = rv[best]; si[k] = li[best];
  }

  // f64 softmax
  double vmax = sv[0];
  double e[KNN]; double s = 0.0;
#pragma unroll
  for (int k = 0; k < KNN; ++k) { e[k] = exp(sv[k] - vmax); s += e[k]; }
  if (lane < KNN) {
    wval[(size_t)m * KNN + lane] = e[lane] / s;
    widx[(size_t)m * KNN + lane] = si[lane];
  }
}

// ---------------- per-pixel weighted vote (f64) + argmax ----------------------
__global__ __launch_bounds__(256) void vote_kernel(const double* __restrict__ wval,
                                                   const int* __restrict__ widx,
                                                   const unsigned char* __restrict__ labT,
                                                   int* __restrict__ out) {
  const int m = blockIdx.x, t = threadIdx.x;
  __shared__ double sw[KNN];
  __shared__ int    si[KNN];
  if (t < KNN) { sw[t] = wval[(size_t)m * KNN + t]; si[t] = widx[(size_t)m * KNN + t]; }
  __syncthreads();
  int lab[KNN]; double w[KNN];
#pragma unroll
  for (int k = 0; k < KNN; ++k) {
    lab[k] = labT[(size_t)si[k] * 256 + t];
    w[k] = sw[k];
  }
  double best = -1.0; int bc = 0;
#pragma unroll
  for (int c = 0; c < NCLS; ++c) {
    double s = 0.0;
#pragma unroll
    for (int k = 0; k < KNN; ++k) s += (lab[k] == c) ? w[k] : 0.0;
    if (s > best) { best = s; bc = c; }   // strict > : first max wins (matches argmax)
  }
  const int b = m / 196, p = m % 196;
  const int py = p / 14, px = p % 14;
  const int i = t >> 4, j = t & 15;
  out[((size_t)b * 224 + py * 16 + i) * 224 + px * 16 + j] = bc;
}

// ---------------- launch ------------------------------------------------------
extern "C" void kernel_launch(void* const* d_in, const int* in_sizes, int n_in,
                              void* d_out, int out_size, void* d_ws, size_t ws_size,
                              hipStream_t stream) {
  const float* test  = (const float*)d_in[0];   // [1568][384]
  const float* train = (const float*)d_in[1];   // [384][50000]
  const int* labels  = (const int*)d_in[2];     // [256][50000]
  int* out = (int*)d_out;
  char* ws = (char*)d_ws;

  unsigned char* labT = (unsigned char*)ws;                    // 12,800,000 B
  float*  simbuf = (float*)(ws + 12800000);                    // 51,380,224 B
  float*  topv   = (float*)(ws + 64180224);                    //  1,053,696 B (1568*168*4)
  int*    topi   = (int*)  (ws + 65233920);                    //  1,053,696 B
  double* wval   = (double*)(ws + 66287616);                   //    250,880 B (1568*20*8)
  int*    widx   = (int*)  (ws + 66538496);                    //    125,440 B

  transpose_labels<<<dim3(782, 4), 256, 0, stream>>>(labels, labT);
  for (int ch = 0; ch < NCHUNKS; ++ch) {
    gemm_chunk<<<dim3(98, 8), 256, 0, stream>>>(test, train, simbuf, ch);
    select_chunk<<<dim3(M_ROWS), 256, 0, stream>>>(simbuf, topv, topi, ch);
  }
  merge_refine<<<dim3(M_ROWS), 64, 0, stream>>>(topv, topi, test, train, wval, widx);
  vote_kernel<<<dim3(M_ROWS), 256, 0, stream>>>(wval, widx, labT, out);
}

// Round 3
// 2147.682 us; speedup vs baseline: 1.0779x; 1.0779x over previous
//
#include <hip/hip_runtime.h>
#include <float.h>

#define N_TRAIN 50000
#define DDIM    384
#define M_ROWS  1568   // 8*196
#define KNN     20
#define K2      24     // per-chunk candidates (margin over 20)
#define NCLS    21
#define CHUNK   8192
#define NCHUNKS 7      // 7*8192 = 57344 >= 50000
#define NCAND   (NCHUNKS * K2)   // 168
#define BM      16
#define BN      1024   // 256 threads * 4 cols

// ---------------- transpose labels [256][50000] i32 -> [50000][256] u8 --------
__global__ __launch_bounds__(256) void transpose_labels(const int* __restrict__ labels,
                                                        unsigned char* __restrict__ labT) {
  __shared__ int tile[64][65];
  const int t  = threadIdx.x;
  const int c0 = blockIdx.x * 64;
  const int r0 = blockIdx.y * 64;
#pragma unroll
  for (int i = 0; i < 16; ++i) {
    int idx = i * 256 + t;
    int r = idx >> 6, c = idx & 63;
    int cc = c0 + c;
    tile[r][c] = (cc < N_TRAIN) ? labels[(size_t)(r0 + r) * N_TRAIN + cc] : 0;
  }
  __syncthreads();
#pragma unroll
  for (int i = 0; i < 16; ++i) {
    int idx = i * 256 + t;
    int c = idx >> 6, r = idx & 63;
    int cc = c0 + c;
    if (cc < N_TRAIN) labT[(size_t)cc * 256 + r0 + r] = (unsigned char)tile[r][c];
  }
}

// ---------------- transpose train [384][50000] f32 -> [50000][384] f32 --------
__global__ __launch_bounds__(256) void transpose_train(const float* __restrict__ train,
                                                       float* __restrict__ trainT) {
  __shared__ float tile[64][65];
  const int t  = threadIdx.x;
  const int c0 = blockIdx.x * 64;   // col (0..50000)
  const int r0 = blockIdx.y * 64;   // row (0..384)
#pragma unroll
  for (int i = 0; i < 16; ++i) {
    int idx = i * 256 + t;
    int r = idx >> 6, c = idx & 63;
    int cc = c0 + c;
    tile[r][c] = (cc < N_TRAIN) ? train[(size_t)(r0 + r) * N_TRAIN + cc] : 0.f;
  }
  __syncthreads();
#pragma unroll
  for (int i = 0; i < 16; ++i) {
    int idx = i * 256 + t;
    int c = idx >> 6, r = idx & 63;
    int cc = c0 + c;
    if (cc < N_TRAIN) trainT[(size_t)cc * DDIM + r0 + r] = tile[r][c];
  }
}

// ---------------- GEMM chunk: sim[m][lc] = dot(test[m], train[:, gc]) ---------
#define FMA4(rr, av) { acc[rr].x = fmaf((av), b.x, acc[rr].x); \
                       acc[rr].y = fmaf((av), b.y, acc[rr].y); \
                       acc[rr].z = fmaf((av), b.z, acc[rr].z); \
                       acc[rr].w = fmaf((av), b.w, acc[rr].w); }

__global__ __launch_bounds__(256) void gemm_chunk(const float* __restrict__ test,
                                                  const float* __restrict__ train,
                                                  float* __restrict__ simbuf, int ch) {
  const int t  = threadIdx.x;
  const int m0 = blockIdx.x * BM;          // row block (98)
  const int lc = blockIdx.y * BN + t * 4;  // local col in chunk
  const int gc = ch * CHUNK + lc;          // global col
  const bool valid = gc < N_TRAIN;         // gc,N both multiples of 4 -> no straddle

  // whole column-block out of range: write -FLT_MAX, skip the FMA loop
  if (ch * CHUNK + blockIdx.y * BN >= N_TRAIN) {
#pragma unroll
    for (int r = 0; r < 16; ++r)
      *(float4*)&simbuf[(size_t)(m0 + r) * CHUNK + lc] =
          make_float4(-FLT_MAX, -FLT_MAX, -FLT_MAX, -FLT_MAX);
    return;
  }

  const int gcc = valid ? gc : (N_TRAIN - 4);
  const float* Bb = train + gcc;

  float4 acc[16];
#pragma unroll
  for (int r = 0; r < 16; ++r) acc[r] = make_float4(0.f, 0.f, 0.f, 0.f);

  for (int d = 0; d < DDIM; d += 4) {
    float4 av[16];
#pragma unroll
    for (int r = 0; r < 16; ++r)
      av[r] = *(const float4*)&test[(size_t)(m0 + r) * DDIM + d];  // block-uniform
#pragma unroll
    for (int dd = 0; dd < 4; ++dd) {
      float4 b = *(const float4*)(Bb + (size_t)(d + dd) * N_TRAIN);
#pragma unroll
      for (int r = 0; r < 16; ++r) {
        float ar = (dd == 0) ? av[r].x : (dd == 1) ? av[r].y : (dd == 2) ? av[r].z : av[r].w;
        FMA4(r, ar)
      }
    }
  }

#pragma unroll
  for (int r = 0; r < 16; ++r) {
    float4 o = valid ? acc[r] : make_float4(-FLT_MAX, -FLT_MAX, -FLT_MAX, -FLT_MAX);
    *(float4*)&simbuf[(size_t)(m0 + r) * CHUNK + lc] = o;
  }
}

// ---------------- per-(row,chunk) exact top-K2 extraction ---------------------
__global__ __launch_bounds__(256) void select_chunk(const float* __restrict__ simbuf,
                                                    float* __restrict__ topv,
                                                    int* __restrict__ topi, int ch) {
  const int t = threadIdx.x;
  const int m = blockIdx.x;
  float v[32];
#pragma unroll
  for (int i = 0; i < 32; ++i) v[i] = simbuf[(size_t)m * CHUNK + i * 256 + t];
  float mv = v[0]; int ms = 0;
#pragma unroll
  for (int i = 1; i < 32; ++i) if (v[i] > mv) { mv = v[i]; ms = i; }

  __shared__ float swv[4];
  __shared__ int   swj[4];

  for (int k = 0; k < K2; ++k) {
    float rv = mv; int rj = ms * 256 + t;   // chunk-local col index
#pragma unroll
    for (int off = 32; off > 0; off >>= 1) {
      float ov = __shfl_xor(rv, off);
      int   oj = __shfl_xor(rj, off);
      if (ov > rv || (ov == rv && oj < rj)) { rv = ov; rj = oj; }
    }
    if ((t & 63) == 0) { swv[t >> 6] = rv; swj[t >> 6] = rj; }
    __syncthreads();
    float wv = swv[0]; int wj = swj[0];
#pragma unroll
    for (int w = 1; w < 4; ++w)
      if (swv[w] > wv || (swv[w] == wv && swj[w] < wj)) { wv = swv[w]; wj = swj[w]; }
    __syncthreads();   // protect swv/swj reuse next iteration
    if (t == (wj & 255)) {
      int slot = wj >> 8;
#pragma unroll
      for (int i = 0; i < 32; ++i) if (i == slot) v[i] = -FLT_MAX;
      mv = v[0]; ms = 0;
#pragma unroll
      for (int i = 1; i < 32; ++i) if (v[i] > mv) { mv = v[i]; ms = i; }
    }
    if (t == 0) {
      topv[(size_t)m * NCAND + ch * K2 + k] = wv;
      topi[(size_t)m * NCAND + ch * K2 + k] = ch * CHUNK + wj;
    }
  }
}

// ---------------- merge 168 -> 24 cand, f64 refine (coalesced), softmax -------
__global__ __launch_bounds__(64) void merge_refine(const float* __restrict__ topv,
                                                   const int* __restrict__ topi,
                                                   const float* __restrict__ test,
                                                   const float* __restrict__ trainT,
                                                   double* __restrict__ wval,
                                                   int* __restrict__ widx) {
  const int m = blockIdx.x;
  const int lane = threadIdx.x;   // 64

  // f32 merge to top-24 candidates (uniform across lanes)
  float lv[K2]; int li[K2];
#pragma unroll
  for (int j = 0; j < K2; ++j) { lv[j] = -FLT_MAX; li[j] = -1; }
  for (int n = 0; n < NCAND; ++n) {
    float nv = topv[(size_t)m * NCAND + n];
    int   ni = topi[(size_t)m * NCAND + n];
    if (nv <= lv[K2 - 1]) continue;
#pragma unroll
    for (int j = 0; j < K2; ++j) {
      bool sw = nv > lv[j];
      float tv = lv[j]; int ti = li[j];
      if (sw) { lv[j] = nv; li[j] = ni; nv = tv; ni = ti; }
    }
  }

  // preload this row's test slice (6 f32 per lane, coalesced)
  float tr[DDIM / 64];
#pragma unroll
  for (int dd = 0; dd < DDIM / 64; ++dd)
    tr[dd] = test[(size_t)m * DDIM + dd * 64 + lane];

  // f64 recompute of the 24 candidate sims (coalesced reads of trainT rows)
  double rv[K2];
#pragma unroll
  for (int c = 0; c < K2; ++c) {
    const int col = li[c];
    const float* Tc = trainT + (size_t)col * DDIM;
    double s = 0.0;
#pragma unroll
    for (int dd = 0; dd < DDIM / 64; ++dd)
      s += (double)tr[dd] * (double)Tc[dd * 64 + lane];
#pragma unroll
    for (int off = 32; off > 0; off >>= 1) s += __shfl_xor(s, off);
    rv[c] = s;   // all lanes hold the full sum (butterfly)
  }

  // select top-20 by (f64 value desc, idx asc)
  bool used[K2];
#pragma unroll
  for (int c = 0; c < K2; ++c) used[c] = false;
  double sv[KNN]; int si[KNN];
  for (int k = 0; k < KNN; ++k) {
    int best = -1;
#pragma unroll
    for (int c = 0; c < K2; ++c) {
      if (used[c]) continue;
      if (best < 0 || rv[c] > rv[best] || (rv[c] == rv[best] && li[c] < li[best])) best = c;
    }
    used[best] = true; sv[k] = rv[best]; si[k] = li[best];
  }

  // f64 softmax
  double vmax = sv[0];
  double e[KNN]; double s = 0.0;
#pragma unroll
  for (int k = 0; k < KNN; ++k) { e[k] = exp(sv[k] - vmax); s += e[k]; }
  if (lane < KNN) {
    wval[(size_t)m * KNN + lane] = e[lane] / s;
    widx[(size_t)m * KNN + lane] = si[lane];
  }
}

// ---------------- per-pixel weighted vote (f64) + argmax ----------------------
__global__ __launch_bounds__(256) void vote_kernel(const double* __restrict__ wval,
                                                   const int* __restrict__ widx,
                                                   const unsigned char* __restrict__ labT,
                                                   int* __restrict__ out) {
  const int m = blockIdx.x, t = threadIdx.x;
  __shared__ double sw[KNN];
  __shared__ int    si[KNN];
  if (t < KNN) { sw[t] = wval[(size_t)m * KNN + t]; si[t] = widx[(size_t)m * KNN + t]; }
  __syncthreads();
  int lab[KNN]; double w[KNN];
#pragma unroll
  for (int k = 0; k < KNN; ++k) {
    lab[k] = labT[(size_t)si[k] * 256 + t];
    w[k] = sw[k];
  }
  double best = -1.0; int bc = 0;
#pragma unroll
  for (int c = 0; c < NCLS; ++c) {
    double s = 0.0;
#pragma unroll
    for (int k = 0; k < KNN; ++k) s += (lab[k] == c) ? w[k] : 0.0;
    if (s > best) { best = s; bc = c; }   // strict > : first max wins (matches argmax)
  }
  const int b = m / 196, p = m % 196;
  const int py = p / 14, px = p % 14;
  const int i = t >> 4, j = t & 15;
  out[((size_t)b * 224 + py * 16 + i) * 224 + px * 16 + j] = bc;
}

// ---------------- launch ------------------------------------------------------
// ws layout (bytes):
//   labT    @ 0          : 12,800,000
//   simbuf  @ 12,800,000 : 51,380,224   (dead after last select_chunk)
//   trainT  @ 12,800,000 : 76,800,000   (ALIASES simbuf; written after it dies)
//   topv    @ 89,600,000 :  1,053,696
//   topi    @ 90,653,696 :  1,053,696
//   wval    @ 91,707,392 :    250,880
//   widx    @ 91,958,272 :    125,440   -> total 92,083,712 B
extern "C" void kernel_launch(void* const* d_in, const int* in_sizes, int n_in,
                              void* d_out, int out_size, void* d_ws, size_t ws_size,
                              hipStream_t stream) {
  const float* test  = (const float*)d_in[0];   // [1568][384]
  const float* train = (const float*)d_in[1];   // [384][50000]
  const int* labels  = (const int*)d_in[2];     // [256][50000]
  int* out = (int*)d_out;
  char* ws = (char*)d_ws;

  unsigned char* labT = (unsigned char*)ws;
  float*  simbuf = (float*)(ws + 12800000);
  float*  trainT = (float*)(ws + 12800000);     // temporal alias of simbuf
  float*  topv   = (float*)(ws + 89600000);
  int*    topi   = (int*)  (ws + 90653696);
  double* wval   = (double*)(ws + 91707392);
  int*    widx   = (int*)  (ws + 91958272);

  transpose_labels<<<dim3(782, 4), 256, 0, stream>>>(labels, labT);
  for (int ch = 0; ch < NCHUNKS; ++ch) {
    gemm_chunk<<<dim3(98, 8), 256, 0, stream>>>(test, train, simbuf, ch);
    select_chunk<<<dim3(M_ROWS), 256, 0, stream>>>(simbuf, topv, topi, ch);
  }
  transpose_train<<<dim3(782, 6), 256, 0, stream>>>(train, trainT);
  merge_refine<<<dim3(M_ROWS), 64, 0, stream>>>(topv, topi, test, trainT, wval, widx);
  vote_kernel<<<dim3(M_ROWS), 256, 0, stream>>>(wval, widx, labT, out);
}

// Round 4
// 1378.831 us; speedup vs baseline: 1.6790x; 1.5576x over previous
//
#include <hip/hip_runtime.h>
#include <float.h>

#define N_TRAIN 50000
#define DDIM    384
#define M_ROWS  1568   // 8*196
#define KNN     20
#define K2      24     // merged candidates (margin over 20)
#define NCLS    21
#define CHUNK   8192
#define NCHUNKS 7      // 7*8192 = 57344 >= 50000
#define NCAND   (NCHUNKS * K2)   // 168
#define BM      16
#define BN      1024   // 256 threads * 4 cols

// ---------------- transpose labels [256][50000] i32 -> [50000][256] u8 --------
__global__ __launch_bounds__(256) void transpose_labels(const int* __restrict__ labels,
                                                        unsigned char* __restrict__ labT) {
  __shared__ int tile[64][65];
  const int t  = threadIdx.x;
  const int c0 = blockIdx.x * 64;
  const int r0 = blockIdx.y * 64;
#pragma unroll
  for (int i = 0; i < 16; ++i) {
    int idx = i * 256 + t;
    int r = idx >> 6, c = idx & 63;
    int cc = c0 + c;
    tile[r][c] = (cc < N_TRAIN) ? labels[(size_t)(r0 + r) * N_TRAIN + cc] : 0;
  }
  __syncthreads();
#pragma unroll
  for (int i = 0; i < 16; ++i) {
    int idx = i * 256 + t;
    int c = idx >> 6, r = idx & 63;
    int cc = c0 + c;
    if (cc < N_TRAIN) labT[(size_t)cc * 256 + r0 + r] = (unsigned char)tile[r][c];
  }
}

// ---------------- transpose train [384][50000] f32 -> [50000][384] f32 --------
__global__ __launch_bounds__(256) void transpose_train(const float* __restrict__ train,
                                                       float* __restrict__ trainT) {
  __shared__ float tile[64][65];
  const int t  = threadIdx.x;
  const int c0 = blockIdx.x * 64;   // col (0..50000)
  const int r0 = blockIdx.y * 64;   // row (0..384)
#pragma unroll
  for (int i = 0; i < 16; ++i) {
    int idx = i * 256 + t;
    int r = idx >> 6, c = idx & 63;
    int cc = c0 + c;
    tile[r][c] = (cc < N_TRAIN) ? train[(size_t)(r0 + r) * N_TRAIN + cc] : 0.f;
  }
  __syncthreads();
#pragma unroll
  for (int i = 0; i < 16; ++i) {
    int idx = i * 256 + t;
    int c = idx >> 6, r = idx & 63;
    int cc = c0 + c;
    if (cc < N_TRAIN) trainT[(size_t)cc * DDIM + r0 + r] = tile[r][c];
  }
}

// ---------------- GEMM chunk: sim[m][lc] = dot(test[m], train[:, gc]) ---------
#define FMA4(rr, av) { acc[rr].x = fmaf((av), b.x, acc[rr].x); \
                       acc[rr].y = fmaf((av), b.y, acc[rr].y); \
                       acc[rr].z = fmaf((av), b.z, acc[rr].z); \
                       acc[rr].w = fmaf((av), b.w, acc[rr].w); }

__global__ __launch_bounds__(256) void gemm_chunk(const float* __restrict__ test,
                                                  const float* __restrict__ train,
                                                  float* __restrict__ simbuf, int ch) {
  const int t  = threadIdx.x;
  const int m0 = blockIdx.x * BM;          // row block (98)
  const int lc = blockIdx.y * BN + t * 4;  // local col in chunk
  const int gc = ch * CHUNK + lc;          // global col
  const bool valid = gc < N_TRAIN;         // gc,N both multiples of 4 -> no straddle

  if (ch * CHUNK + blockIdx.y * BN >= N_TRAIN) {
#pragma unroll
    for (int r = 0; r < 16; ++r)
      *(float4*)&simbuf[(size_t)(m0 + r) * CHUNK + lc] =
          make_float4(-FLT_MAX, -FLT_MAX, -FLT_MAX, -FLT_MAX);
    return;
  }

  const int gcc = valid ? gc : (N_TRAIN - 4);
  const float* Bb = train + gcc;

  float4 acc[16];
#pragma unroll
  for (int r = 0; r < 16; ++r) acc[r] = make_float4(0.f, 0.f, 0.f, 0.f);

  for (int d = 0; d < DDIM; d += 4) {
    float4 av[16];
#pragma unroll
    for (int r = 0; r < 16; ++r)
      av[r] = *(const float4*)&test[(size_t)(m0 + r) * DDIM + d];  // block-uniform
#pragma unroll
    for (int dd = 0; dd < 4; ++dd) {
      float4 b = *(const float4*)(Bb + (size_t)(d + dd) * N_TRAIN);
#pragma unroll
      for (int r = 0; r < 16; ++r) {
        float ar = (dd == 0) ? av[r].x : (dd == 1) ? av[r].y : (dd == 2) ? av[r].z : av[r].w;
        FMA4(r, ar)
      }
    }
  }

#pragma unroll
  for (int r = 0; r < 16; ++r) {
    float4 o = valid ? acc[r] : make_float4(-FLT_MAX, -FLT_MAX, -FLT_MAX, -FLT_MAX);
    *(float4*)&simbuf[(size_t)(m0 + r) * CHUNK + lc] = o;
  }
}

// ---------------- per-(row,chunk) exact top-K2 extraction ---------------------
__global__ __launch_bounds__(256) void select_chunk(const float* __restrict__ simbuf,
                                                    float* __restrict__ topv,
                                                    int* __restrict__ topi, int ch) {
  const int t = threadIdx.x;
  const int m = blockIdx.x;
  float v[32];
#pragma unroll
  for (int i = 0; i < 32; ++i) v[i] = simbuf[(size_t)m * CHUNK + i * 256 + t];
  float mv = v[0]; int ms = 0;
#pragma unroll
  for (int i = 1; i < 32; ++i) if (v[i] > mv) { mv = v[i]; ms = i; }

  __shared__ float swv[4];
  __shared__ int   swj[4];

  for (int k = 0; k < K2; ++k) {
    float rv = mv; int rj = ms * 256 + t;   // chunk-local col index
#pragma unroll
    for (int off = 32; off > 0; off >>= 1) {
      float ov = __shfl_xor(rv, off);
      int   oj = __shfl_xor(rj, off);
      if (ov > rv || (ov == rv && oj < rj)) { rv = ov; rj = oj; }
    }
    if ((t & 63) == 0) { swv[t >> 6] = rv; swj[t >> 6] = rj; }
    __syncthreads();
    float wv = swv[0]; int wj = swj[0];
#pragma unroll
    for (int w = 1; w < 4; ++w)
      if (swv[w] > wv || (swv[w] == wv && swj[w] < wj)) { wv = swv[w]; wj = swj[w]; }
    __syncthreads();   // protect swv/swj reuse next iteration
    if (t == (wj & 255)) {
      int slot = wj >> 8;
#pragma unroll
      for (int i = 0; i < 32; ++i) if (i == slot) v[i] = -FLT_MAX;
      mv = v[0]; ms = 0;
#pragma unroll
      for (int i = 1; i < 32; ++i) if (v[i] > mv) { mv = v[i]; ms = i; }
    }
    if (t == 0) {
      topv[(size_t)m * NCAND + ch * K2 + k] = wv;
      topi[(size_t)m * NCAND + ch * K2 + k] = ch * CHUNK + wj;
    }
  }
}

// ---------------- merge (rank-select) -> f64 refine -> top-20 -> softmax ------
// 256 threads per row. Rank-based selection: (value desc, idx asc) is a total
// order (idx distinct), so ranks are unique and rank<K2 IS the top-K2 set.
__global__ __launch_bounds__(256) void merge_refine(const float* __restrict__ topv,
                                                    const int* __restrict__ topi,
                                                    const float* __restrict__ test,
                                                    const float* __restrict__ trainT,
                                                    double* __restrict__ wval,
                                                    int* __restrict__ widx) {
  const int m = blockIdx.x;
  const int t = threadIdx.x;
  __shared__ float  cv[NCAND];
  __shared__ int    ci[NCAND];
  __shared__ int    selIdx[K2];
  __shared__ double rvs[K2];
  __shared__ double sv2[K2];
  __shared__ int    si2[K2];
  __shared__ double earr[KNN];

  if (t < NCAND) {
    cv[t] = topv[(size_t)m * NCAND + t];
    ci[t] = topi[(size_t)m * NCAND + t];
  }
  __syncthreads();

  // parallel rank among 168 f32 candidates
  if (t < NCAND) {
    float v = cv[t]; int id = ci[t];
    int r = 0;
    for (int n = 0; n < NCAND; ++n) {
      float nv = cv[n]; int ni = ci[n];
      r += (nv > v || (nv == v && ni < id)) ? 1 : 0;
    }
    if (r < K2) selIdx[r] = id;
  }
  __syncthreads();

  // f64 refine: wave w handles candidates w, w+4, ... (6 each), lanes over d
  const int wid = t >> 6, lane = t & 63;
  float tr[DDIM / 64];
#pragma unroll
  for (int dd = 0; dd < DDIM / 64; ++dd)
    tr[dd] = test[(size_t)m * DDIM + dd * 64 + lane];
#pragma unroll 1
  for (int c = wid; c < K2; c += 4) {
    const int col = selIdx[c];
    const float* Tc = trainT + (size_t)col * DDIM;
    double s = 0.0;
#pragma unroll
    for (int dd = 0; dd < DDIM / 64; ++dd)
      s += (double)tr[dd] * (double)Tc[dd * 64 + lane];
#pragma unroll
    for (int off = 32; off > 0; off >>= 1) s += __shfl_xor(s, off);
    if (lane == 0) rvs[c] = s;
  }
  __syncthreads();

  // rank-select top-20 of 24 in f64
  if (t < K2) {
    double v = rvs[t]; int id = selIdx[t];
    int r = 0;
    for (int n = 0; n < K2; ++n)
      r += (rvs[n] > v || (rvs[n] == v && selIdx[n] < id)) ? 1 : 0;
    sv2[r] = v; si2[r] = id;
  }
  __syncthreads();

  // f64 softmax over ranks 0..19 (sv2[0] is the max)
  if (t < KNN) earr[t] = exp(sv2[t] - sv2[0]);
  __syncthreads();
  if (t < KNN) {
    double ssum = 0.0;
    for (int k = 0; k < KNN; ++k) ssum += earr[k];   // fixed ascending order
    wval[(size_t)m * KNN + t] = earr[t] / ssum;
    widx[(size_t)m * KNN + t] = si2[t];
  }
}

// ---------------- per-pixel weighted vote (f64) + argmax ----------------------
// Labels packed into 5 u32 regs (static indices only); weights stay in LDS and
// are re-read per use; class loop NOT unrolled -> one live f64 accumulator.
__global__ __launch_bounds__(256) void vote_kernel(const double* __restrict__ wval,
                                                   const int* __restrict__ widx,
                                                   const unsigned char* __restrict__ labT,
                                                   int* __restrict__ out) {
  const int m = blockIdx.x, t = threadIdx.x;
  __shared__ double sw[KNN];
  __shared__ int    si[KNN];
  if (t < KNN) { sw[t] = wval[(size_t)m * KNN + t]; si[t] = widx[(size_t)m * KNN + t]; }
  __syncthreads();

  unsigned int packed[5];
#pragma unroll
  for (int q = 0; q < 5; ++q) {
    unsigned int p = 0;
#pragma unroll
    for (int j = 0; j < 4; ++j)
      p |= (unsigned int)labT[(size_t)si[q * 4 + j] * 256 + t] << (8 * j);
    packed[q] = p;
  }

  double best = -1.0; int bc = 0;
#pragma unroll 1
  for (int c = 0; c < NCLS; ++c) {
    double s = 0.0;
#pragma unroll
    for (int k = 0; k < KNN; ++k) {
      unsigned int lab = (packed[k >> 2] >> ((k & 3) * 8)) & 255u;
      s += (lab == (unsigned int)c) ? sw[k] : 0.0;
    }
    if (s > best) { best = s; bc = c; }   // strict > : first max wins (matches argmax)
  }

  const int b = m / 196, p = m % 196;
  const int py = p / 14, px = p % 14;
  const int i = t >> 4, j = t & 15;
  out[((size_t)b * 224 + py * 16 + i) * 224 + px * 16 + j] = bc;
}

// ---------------- launch ------------------------------------------------------
// ws layout (bytes):
//   labT    @ 0          : 12,800,000
//   simbuf  @ 12,800,000 : 51,380,224   (dead after last select_chunk)
//   trainT  @ 12,800,000 : 76,800,000   (ALIASES simbuf; written after it dies)
//   topv    @ 89,600,000 :  1,053,696
//   topi    @ 90,653,696 :  1,053,696
//   wval    @ 91,707,392 :    250,880
//   widx    @ 91,958,272 :    125,440   -> total 92,083,712 B
extern "C" void kernel_launch(void* const* d_in, const int* in_sizes, int n_in,
                              void* d_out, int out_size, void* d_ws, size_t ws_size,
                              hipStream_t stream) {
  const float* test  = (const float*)d_in[0];   // [1568][384]
  const float* train = (const float*)d_in[1];   // [384][50000]
  const int* labels  = (const int*)d_in[2];     // [256][50000]
  int* out = (int*)d_out;
  char* ws = (char*)d_ws;

  unsigned char* labT = (unsigned char*)ws;
  float*  simbuf = (float*)(ws + 12800000);
  float*  trainT = (float*)(ws + 12800000);     // temporal alias of simbuf
  float*  topv   = (float*)(ws + 89600000);
  int*    topi   = (int*)  (ws + 90653696);
  double* wval   = (double*)(ws + 91707392);
  int*    widx   = (int*)  (ws + 91958272);

  transpose_labels<<<dim3(782, 4), 256, 0, stream>>>(labels, labT);
  for (int ch = 0; ch < NCHUNKS; ++ch) {
    gemm_chunk<<<dim3(98, 8), 256, 0, stream>>>(test, train, simbuf, ch);
    select_chunk<<<dim3(M_ROWS), 256, 0, stream>>>(simbuf, topv, topi, ch);
  }
  transpose_train<<<dim3(782, 6), 256, 0, stream>>>(train, trainT);
  merge_refine<<<dim3(M_ROWS), 256, 0, stream>>>(topv, topi, test, trainT, wval, widx);
  vote_kernel<<<dim3(M_ROWS), 256, 0, stream>>>(wval, widx, labT, out);
}

// Round 5
// 809.860 us; speedup vs baseline: 2.8586x; 1.7026x over previous
//
#include <hip/hip_runtime.h>
#include <float.h>

#define N_TRAIN 50000
#define DDIM    384
#define M_ROWS  1568   // 8*196
#define KNN     20
#define K2      24     // per-chunk / merged candidates (margin over 20)
#define NCLS    21
#define CHUNK   6144
#define NCHUNKS 9      // 9*6144 = 55296 >= 50000
#define NCAND   (NCHUNKS * K2)   // 216

typedef __attribute__((ext_vector_type(8))) short bf16x8;
typedef __attribute__((ext_vector_type(4))) float f32x4;

// round-to-nearest-even f32 -> bf16
static __device__ __forceinline__ unsigned short f2bf(float f) {
  unsigned int u = __float_as_uint(f);
  unsigned int r = (u + 0x7fffu + ((u >> 16) & 1u)) >> 16;
  return (unsigned short)r;
}

// ---------------- transpose labels [256][50000] i32 -> [50000][256] u8 --------
__global__ __launch_bounds__(256) void transpose_labels(const int* __restrict__ labels,
                                                        unsigned char* __restrict__ labT) {
  __shared__ int tile[64][65];
  const int t  = threadIdx.x;
  const int c0 = blockIdx.x * 64;
  const int r0 = blockIdx.y * 64;
#pragma unroll
  for (int i = 0; i < 16; ++i) {
    int idx = i * 256 + t;
    int r = idx >> 6, c = idx & 63;
    int cc = c0 + c;
    tile[r][c] = (cc < N_TRAIN) ? labels[(size_t)(r0 + r) * N_TRAIN + cc] : 0;
  }
  __syncthreads();
#pragma unroll
  for (int i = 0; i < 16; ++i) {
    int idx = i * 256 + t;
    int c = idx >> 6, r = idx & 63;
    int cc = c0 + c;
    if (cc < N_TRAIN) labT[(size_t)cc * 256 + r0 + r] = (unsigned char)tile[r][c];
  }
}

// ------------- transpose+convert train [384][50000] f32 -> bhT [50000][384] bf16
__global__ __launch_bounds__(256) void conv_bhT(const float* __restrict__ train,
                                                unsigned short* __restrict__ bhT) {
  __shared__ float tile[64][65];
  const int t  = threadIdx.x;
  const int c0 = blockIdx.x * 64;   // col
  const int r0 = blockIdx.y * 64;   // k
#pragma unroll
  for (int i = 0; i < 16; ++i) {
    int idx = i * 256 + t;
    int r = idx >> 6, c = idx & 63;
    int cc = c0 + c;
    tile[r][c] = (cc < N_TRAIN) ? train[(size_t)(r0 + r) * N_TRAIN + cc] : 0.f;
  }
  __syncthreads();
#pragma unroll
  for (int i = 0; i < 16; ++i) {
    int idx = i * 256 + t;
    int c = idx >> 6, r = idx & 63;
    int cc = c0 + c;
    if (cc < N_TRAIN) bhT[(size_t)cc * DDIM + r0 + r] = f2bf(tile[r][c]);
  }
}

// ---------------- transpose train [384][50000] f32 -> [50000][384] f32 --------
__global__ __launch_bounds__(256) void transpose_train(const float* __restrict__ train,
                                                       float* __restrict__ trainT) {
  __shared__ float tile[64][65];
  const int t  = threadIdx.x;
  const int c0 = blockIdx.x * 64;
  const int r0 = blockIdx.y * 64;
#pragma unroll
  for (int i = 0; i < 16; ++i) {
    int idx = i * 256 + t;
    int r = idx >> 6, c = idx & 63;
    int cc = c0 + c;
    tile[r][c] = (cc < N_TRAIN) ? train[(size_t)(r0 + r) * N_TRAIN + cc] : 0.f;
  }
  __syncthreads();
#pragma unroll
  for (int i = 0; i < 16; ++i) {
    int idx = i * 256 + t;
    int c = idx >> 6, r = idx & 63;
    int cc = c0 + c;
    if (cc < N_TRAIN) trainT[(size_t)cc * DDIM + r0 + r] = tile[r][c];
  }
}

// ---------------- MFMA bf16 GEMM chunk: simbuf[m][lc] ~= test[m] . train[:,gc]
// block tile 64m x 256n, 4 waves (2x2), wave tile 32x128, K_STEP=64.
#define BMT 64
#define BNT 256
#define KST 64
#define LDP 72   // LDS row stride in bf16 units (144 B: 16B-aligned, bank-friendly)

__global__ __launch_bounds__(256) void mfma_gemm(const float* __restrict__ test,
                                                 const unsigned short* __restrict__ bhT,
                                                 float* __restrict__ simbuf, int ch) {
  __shared__ unsigned short Al[BMT * LDP];   //  9216 B
  __shared__ unsigned short Bl[BNT * LDP];   // 36864 B
  const int t   = threadIdx.x;
  const int m0  = blockIdx.x * BMT;
  const int nb  = blockIdx.y * BNT;          // chunk-local col base
  const int gn0 = ch * CHUNK + nb;           // global col base

  if (gn0 >= N_TRAIN) {                      // fully padded block
    for (int r = 0; r < BMT; ++r) {
      int m = m0 + r;
      if (m >= M_ROWS) break;
      simbuf[(size_t)m * CHUNK + nb + t] = -FLT_MAX;
    }
    return;
  }

  const int wid = t >> 6, lane = t & 63;
  const int wr = wid >> 1, wc = wid & 1;
  const int l15 = lane & 15, l4 = lane >> 4;

  f32x4 acc[2][8];
  const f32x4 zero = {0.f, 0.f, 0.f, 0.f};
#pragma unroll
  for (int f = 0; f < 2; ++f)
#pragma unroll
    for (int n = 0; n < 8; ++n) acc[f][n] = zero;

  for (int ks = 0; ks < DDIM / KST; ++ks) {
    __syncthreads();
    // stage A: 64 rows x 64 k from f32 test (convert in-reg)
#pragma unroll
    for (int p = 0; p < 4; ++p) {
      int flat = p * 256 + t;
      int r = flat >> 4, q = flat & 15;
      int mm = m0 + r; if (mm > M_ROWS - 1) mm = M_ROWS - 1;
      float4 v = *(const float4*)&test[(size_t)mm * DDIM + ks * KST + q * 4];
      ushort4 h;
      h.x = f2bf(v.x); h.y = f2bf(v.y); h.z = f2bf(v.z); h.w = f2bf(v.w);
      *(ushort4*)&Al[r * LDP + q * 4] = h;
    }
    // stage B: 256 n x 64 k direct bf16 16B chunks from bhT [n][k]
#pragma unroll
    for (int p = 0; p < 8; ++p) {
      int flat = p * 256 + t;
      int n = flat >> 3, kq = flat & 7;
      int gc = gn0 + n; if (gc > N_TRAIN - 1) gc = N_TRAIN - 1;
      uint4 v = *(const uint4*)&bhT[(size_t)gc * DDIM + ks * KST + kq * 8];
      *(uint4*)&Bl[n * LDP + kq * 8] = v;
    }
    __syncthreads();
#pragma unroll
    for (int k2 = 0; k2 < 2; ++k2) {
      bf16x8 a[2], b[8];
#pragma unroll
      for (int f = 0; f < 2; ++f)
        a[f] = *(bf16x8*)&Al[(wr * 32 + f * 16 + l15) * LDP + k2 * 32 + l4 * 8];
#pragma unroll
      for (int n = 0; n < 8; ++n)
        b[n] = *(bf16x8*)&Bl[(wc * 128 + n * 16 + l15) * LDP + k2 * 32 + l4 * 8];
#pragma unroll
      for (int f = 0; f < 2; ++f)
#pragma unroll
        for (int n = 0; n < 8; ++n)
          acc[f][n] = __builtin_amdgcn_mfma_f32_16x16x32_bf16(a[f], b[n], acc[f][n], 0, 0, 0);
    }
  }

  // epilogue: C[row=(lane>>4)*4+reg][col=lane&15] per 16x16 frag
#pragma unroll
  for (int f = 0; f < 2; ++f) {
    int mbase = m0 + wr * 32 + f * 16 + l4 * 4;
#pragma unroll
    for (int n = 0; n < 8; ++n) {
      int cl = nb + wc * 128 + n * 16 + l15;
      bool cv = (ch * CHUNK + cl) < N_TRAIN;
#pragma unroll
      for (int r = 0; r < 4; ++r) {
        int m = mbase + r;
        if (m < M_ROWS)
          simbuf[(size_t)m * CHUNK + cl] = cv ? acc[f][n][r] : -FLT_MAX;
      }
    }
  }
}

// ---------------- per-(row,chunk) exact top-K2 extraction ---------------------
__global__ __launch_bounds__(256) void select_chunk(const float* __restrict__ simbuf,
                                                    float* __restrict__ topv,
                                                    unsigned short* __restrict__ topi, int ch) {
  const int t = threadIdx.x;
  const int m = blockIdx.x;
  float v[24];
#pragma unroll
  for (int i = 0; i < 24; ++i) v[i] = simbuf[(size_t)m * CHUNK + i * 256 + t];
  float mv = v[0]; int ms = 0;
#pragma unroll
  for (int i = 1; i < 24; ++i) if (v[i] > mv) { mv = v[i]; ms = i; }

  __shared__ float swv[4];
  __shared__ int   swj[4];

  for (int k = 0; k < K2; ++k) {
    float rv = mv; int rj = ms * 256 + t;   // chunk-local col index
#pragma unroll
    for (int off = 32; off > 0; off >>= 1) {
      float ov = __shfl_xor(rv, off);
      int   oj = __shfl_xor(rj, off);
      if (ov > rv || (ov == rv && oj < rj)) { rv = ov; rj = oj; }
    }
    if ((t & 63) == 0) { swv[t >> 6] = rv; swj[t >> 6] = rj; }
    __syncthreads();
    float wv = swv[0]; int wj = swj[0];
#pragma unroll
    for (int w = 1; w < 4; ++w)
      if (swv[w] > wv || (swv[w] == wv && swj[w] < wj)) { wv = swv[w]; wj = swj[w]; }
    __syncthreads();
    if (t == (wj & 255)) {
      int slot = wj >> 8;
#pragma unroll
      for (int i = 0; i < 24; ++i) if (i == slot) v[i] = -FLT_MAX;
      mv = v[0]; ms = 0;
#pragma unroll
      for (int i = 1; i < 24; ++i) if (v[i] > mv) { mv = v[i]; ms = i; }
    }
    if (t == 0) {
      topv[(size_t)m * NCAND + ch * K2 + k] = wv;
      topi[(size_t)m * NCAND + ch * K2 + k] = (unsigned short)wj;
    }
  }
}

// ---------------- merge 216 -> top-24 candidate indices (rank-select) ---------
__global__ __launch_bounds__(256) void merge24(const float* __restrict__ topv,
                                               const unsigned short* __restrict__ topi,
                                               int* __restrict__ selIdx) {
  const int m = blockIdx.x, t = threadIdx.x;
  __shared__ float cv[NCAND];
  __shared__ int   ci[NCAND];
  if (t < NCAND) {
    cv[t] = topv[(size_t)m * NCAND + t];
    ci[t] = (t / K2) * CHUNK + (int)topi[(size_t)m * NCAND + t];
  }
  __syncthreads();
  if (t < NCAND) {
    float v = cv[t]; int id = ci[t];
    int r = 0;
    for (int n = 0; n < NCAND; ++n) {
      float nv = cv[n]; int ni = ci[n];
      r += (nv > v || (nv == v && ni < id)) ? 1 : 0;
    }
    if (r < K2) selIdx[(size_t)m * K2 + r] = id;
  }
}

// ---------------- f64 refine of 24 cands -> exact top-20 -> f64 softmax -------
__global__ __launch_bounds__(256) void refine_softmax(const int* __restrict__ selIdx,
                                                      const float* __restrict__ test,
                                                      const float* __restrict__ trainT,
                                                      double* __restrict__ wval,
                                                      int* __restrict__ widx) {
  const int m = blockIdx.x, t = threadIdx.x;
  __shared__ int    sIdx[K2];
  __shared__ double rvs[K2];
  __shared__ double sv2[K2];
  __shared__ int    si2[K2];
  __shared__ double earr[KNN];
  if (t < K2) sIdx[t] = selIdx[(size_t)m * K2 + t];
  __syncthreads();

  const int wid = t >> 6, lane = t & 63;
  float tr[DDIM / 64];
#pragma unroll
  for (int dd = 0; dd < DDIM / 64; ++dd)
    tr[dd] = test[(size_t)m * DDIM + dd * 64 + lane];
#pragma unroll 1
  for (int c = wid; c < K2; c += 4) {
    const float* Tc = trainT + (size_t)sIdx[c] * DDIM;
    double s = 0.0;
#pragma unroll
    for (int dd = 0; dd < DDIM / 64; ++dd)
      s += (double)tr[dd] * (double)Tc[dd * 64 + lane];
#pragma unroll
    for (int off = 32; off > 0; off >>= 1) s += __shfl_xor(s, off);
    if (lane == 0) rvs[c] = s;
  }
  __syncthreads();

  if (t < K2) {
    double v = rvs[t]; int id = sIdx[t];
    int r = 0;
    for (int n = 0; n < K2; ++n)
      r += (rvs[n] > v || (rvs[n] == v && sIdx[n] < id)) ? 1 : 0;
    sv2[r] = v; si2[r] = id;
  }
  __syncthreads();

  if (t < KNN) earr[t] = exp(sv2[t] - sv2[0]);
  __syncthreads();
  if (t < KNN) {
    double ssum = 0.0;
    for (int k = 0; k < KNN; ++k) ssum += earr[k];
    wval[(size_t)m * KNN + t] = earr[t] / ssum;
    widx[(size_t)m * KNN + t] = si2[t];
  }
}

// ---------------- per-pixel weighted vote (f64) + argmax ----------------------
__global__ __launch_bounds__(256) void vote_kernel(const double* __restrict__ wval,
                                                   const int* __restrict__ widx,
                                                   const unsigned char* __restrict__ labT,
                                                   int* __restrict__ out) {
  const int m = blockIdx.x, t = threadIdx.x;
  __shared__ double sw[KNN];
  __shared__ int    si[KNN];
  if (t < KNN) { sw[t] = wval[(size_t)m * KNN + t]; si[t] = widx[(size_t)m * KNN + t]; }
  __syncthreads();

  unsigned int packed[5];
#pragma unroll
  for (int q = 0; q < 5; ++q) {
    unsigned int p = 0;
#pragma unroll
    for (int j = 0; j < 4; ++j)
      p |= (unsigned int)labT[(size_t)si[q * 4 + j] * 256 + t] << (8 * j);
    packed[q] = p;
  }

  double best = -1.0; int bc = 0;
#pragma unroll 1
  for (int c = 0; c < NCLS; ++c) {
    double s = 0.0;
#pragma unroll
    for (int k = 0; k < KNN; ++k) {
      unsigned int lab = (packed[k >> 2] >> ((k & 3) * 8)) & 255u;
      s += (lab == (unsigned int)c) ? sw[k] : 0.0;
    }
    if (s > best) { best = s; bc = c; }
  }

  const int b = m / 196, p = m % 196;
  const int py = p / 14, px = p % 14;
  const int i = t >> 4, j = t & 15;
  out[((size_t)b * 224 + py * 16 + i) * 224 + px * 16 + j] = bc;
}

// ---------------- launch ------------------------------------------------------
// ws layout (bytes), total 91,917,824 (< 92,083,712 proven-safe):
//   labT    @ 0          : 12,800,000
//   simbuf  @ 12,800,000 : 38,535,168  (f32, dead after last select)
//   bhT     @ 51,335,168 : 38,400,000  (bf16, dead after last mfma_gemm)
//   trainT  @ 12,800,000 : 76,800,000  (ALIASES simbuf+bhT; written after both die)
//   topv    @ 89,735,168 :  1,354,752  (dead after merge24)
//   topi    @ 91,089,920 :    677,376  (u16; dead after merge24)
//   selIdx  @ 91,767,296 :    150,528
//   wval    @ 89,735,168 :    250,880  (reuses dead topv region)
//   widx    @ 89,986,048 :    125,440
extern "C" void kernel_launch(void* const* d_in, const int* in_sizes, int n_in,
                              void* d_out, int out_size, void* d_ws, size_t ws_size,
                              hipStream_t stream) {
  const float* test  = (const float*)d_in[0];   // [1568][384]
  const float* train = (const float*)d_in[1];   // [384][50000]
  const int* labels  = (const int*)d_in[2];     // [256][50000]
  int* out = (int*)d_out;
  char* ws = (char*)d_ws;

  unsigned char*  labT   = (unsigned char*)ws;
  float*          simbuf = (float*)(ws + 12800000);
  unsigned short* bhT    = (unsigned short*)(ws + 51335168);
  float*          trainT = (float*)(ws + 12800000);   // alias (after simbuf+bhT dead)
  float*          topv   = (float*)(ws + 89735168);
  unsigned short* topi   = (unsigned short*)(ws + 91089920);
  int*            selIdx = (int*)(ws + 91767296);
  double*         wval   = (double*)(ws + 89735168);  // reuses dead topv
  int*            widx   = (int*)(ws + 89986048);

  transpose_labels<<<dim3(782, 4), 256, 0, stream>>>(labels, labT);
  conv_bhT<<<dim3(782, 6), 256, 0, stream>>>(train, bhT);
  for (int ch = 0; ch < NCHUNKS; ++ch) {
    mfma_gemm<<<dim3(25, 24), 256, 0, stream>>>(test, bhT, simbuf, ch);
    select_chunk<<<dim3(M_ROWS), 256, 0, stream>>>(simbuf, topv, topi, ch);
  }
  merge24<<<dim3(M_ROWS), 256, 0, stream>>>(topv, topi, selIdx);
  transpose_train<<<dim3(782, 6), 256, 0, stream>>>(train, trainT);
  refine_softmax<<<dim3(M_ROWS), 256, 0, stream>>>(selIdx, test, trainT, wval, widx);
  vote_kernel<<<dim3(M_ROWS), 256, 0, stream>>>(wval, widx, labT, out);
}

// Round 6
// 554.049 us; speedup vs baseline: 4.1784x; 1.4617x over previous
//
#include <hip/hip_runtime.h>
#include <float.h>

#define N_TRAIN 50000
#define DDIM    384
#define M_ROWS  1568   // 8*196
#define KNN     20
#define K2      24     // per-chunk / merged candidates (margin over 20)
#define NCLS    21
#define CHUNK   6144
#define NCHUNKS 9      // 9*6144 = 55296 >= 50000
#define NCAND   (NCHUNKS * K2)   // 216
#define CAP     512

typedef __attribute__((ext_vector_type(8))) short bf16x8;
typedef __attribute__((ext_vector_type(4))) float f32x4;

// round-to-nearest-even f32 -> bf16
static __device__ __forceinline__ unsigned short f2bf(float f) {
  unsigned int u = __float_as_uint(f);
  unsigned int r = (u + 0x7fffu + ((u >> 16) & 1u)) >> 16;
  return (unsigned short)r;
}

// ---------------- transpose labels [256][50000] i32 -> [50000][256] u8 --------
__global__ __launch_bounds__(256) void transpose_labels(const int* __restrict__ labels,
                                                        unsigned char* __restrict__ labT) {
  __shared__ int tile[64][65];
  const int t  = threadIdx.x;
  const int c0 = blockIdx.x * 64;
  const int r0 = blockIdx.y * 64;
#pragma unroll
  for (int i = 0; i < 16; ++i) {
    int idx = i * 256 + t;
    int r = idx >> 6, c = idx & 63;
    int cc = c0 + c;
    tile[r][c] = (cc < N_TRAIN) ? labels[(size_t)(r0 + r) * N_TRAIN + cc] : 0;
  }
  __syncthreads();
#pragma unroll
  for (int i = 0; i < 16; ++i) {
    int idx = i * 256 + t;
    int c = idx >> 6, r = idx & 63;
    int cc = c0 + c;
    if (cc < N_TRAIN) labT[(size_t)cc * 256 + r0 + r] = (unsigned char)tile[r][c];
  }
}

// ------------- transpose+convert train [384][50000] f32 -> bhT [50000][384] bf16
__global__ __launch_bounds__(256) void conv_bhT(const float* __restrict__ train,
                                                unsigned short* __restrict__ bhT) {
  __shared__ float tile[64][65];
  const int t  = threadIdx.x;
  const int c0 = blockIdx.x * 64;   // col
  const int r0 = blockIdx.y * 64;   // k
#pragma unroll
  for (int i = 0; i < 16; ++i) {
    int idx = i * 256 + t;
    int r = idx >> 6, c = idx & 63;
    int cc = c0 + c;
    tile[r][c] = (cc < N_TRAIN) ? train[(size_t)(r0 + r) * N_TRAIN + cc] : 0.f;
  }
  __syncthreads();
#pragma unroll
  for (int i = 0; i < 16; ++i) {
    int idx = i * 256 + t;
    int c = idx >> 6, r = idx & 63;
    int cc = c0 + c;
    if (cc < N_TRAIN) bhT[(size_t)cc * DDIM + r0 + r] = f2bf(tile[r][c]);
  }
}

// ---------------- transpose train [384][50000] f32 -> [50000][384] f32 --------
__global__ __launch_bounds__(256) void transpose_train(const float* __restrict__ train,
                                                       float* __restrict__ trainT) {
  __shared__ float tile[64][65];
  const int t  = threadIdx.x;
  const int c0 = blockIdx.x * 64;
  const int r0 = blockIdx.y * 64;
#pragma unroll
  for (int i = 0; i < 16; ++i) {
    int idx = i * 256 + t;
    int r = idx >> 6, c = idx & 63;
    int cc = c0 + c;
    tile[r][c] = (cc < N_TRAIN) ? train[(size_t)(r0 + r) * N_TRAIN + cc] : 0.f;
  }
  __syncthreads();
#pragma unroll
  for (int i = 0; i < 16; ++i) {
    int idx = i * 256 + t;
    int c = idx >> 6, r = idx & 63;
    int cc = c0 + c;
    if (cc < N_TRAIN) trainT[(size_t)cc * DDIM + r0 + r] = tile[r][c];
  }
}

// ---------------- MFMA bf16 GEMM chunk: simbuf[m][lc] ~= test[m] . train[:,gc]
// block tile 64m x 256n, 4 waves (2x2), wave tile 32x128, K_STEP=64.
#define BMT 64
#define BNT 256
#define KST 64
#define LDP 72   // LDS row stride in bf16 units (144 B: 16B-aligned, bank-friendly)

__global__ __launch_bounds__(256) void mfma_gemm(const float* __restrict__ test,
                                                 const unsigned short* __restrict__ bhT,
                                                 float* __restrict__ simbuf, int ch) {
  __shared__ unsigned short Al[BMT * LDP];   //  9216 B
  __shared__ unsigned short Bl[BNT * LDP];   // 36864 B
  const int t   = threadIdx.x;
  const int m0  = blockIdx.x * BMT;
  const int nb  = blockIdx.y * BNT;          // chunk-local col base
  const int gn0 = ch * CHUNK + nb;           // global col base

  if (gn0 >= N_TRAIN) {                      // fully padded block
    for (int r = 0; r < BMT; ++r) {
      int m = m0 + r;
      if (m >= M_ROWS) break;
      simbuf[(size_t)m * CHUNK + nb + t] = -FLT_MAX;
    }
    return;
  }

  const int wid = t >> 6, lane = t & 63;
  const int wr = wid >> 1, wc = wid & 1;
  const int l15 = lane & 15, l4 = lane >> 4;

  f32x4 acc[2][8];
  const f32x4 zero = {0.f, 0.f, 0.f, 0.f};
#pragma unroll
  for (int f = 0; f < 2; ++f)
#pragma unroll
    for (int n = 0; n < 8; ++n) acc[f][n] = zero;

  for (int ks = 0; ks < DDIM / KST; ++ks) {
    __syncthreads();
    // stage A: 64 rows x 64 k from f32 test (convert in-reg)
#pragma unroll
    for (int p = 0; p < 4; ++p) {
      int flat = p * 256 + t;
      int r = flat >> 4, q = flat & 15;
      int mm = m0 + r; if (mm > M_ROWS - 1) mm = M_ROWS - 1;
      float4 v = *(const float4*)&test[(size_t)mm * DDIM + ks * KST + q * 4];
      ushort4 h;
      h.x = f2bf(v.x); h.y = f2bf(v.y); h.z = f2bf(v.z); h.w = f2bf(v.w);
      *(ushort4*)&Al[r * LDP + q * 4] = h;
    }
    // stage B: 256 n x 64 k direct bf16 16B chunks from bhT [n][k]
#pragma unroll
    for (int p = 0; p < 8; ++p) {
      int flat = p * 256 + t;
      int n = flat >> 3, kq = flat & 7;
      int gc = gn0 + n; if (gc > N_TRAIN - 1) gc = N_TRAIN - 1;
      uint4 v = *(const uint4*)&bhT[(size_t)gc * DDIM + ks * KST + kq * 8];
      *(uint4*)&Bl[n * LDP + kq * 8] = v;
    }
    __syncthreads();
#pragma unroll
    for (int k2 = 0; k2 < 2; ++k2) {
      bf16x8 a[2], b[8];
#pragma unroll
      for (int f = 0; f < 2; ++f)
        a[f] = *(bf16x8*)&Al[(wr * 32 + f * 16 + l15) * LDP + k2 * 32 + l4 * 8];
#pragma unroll
      for (int n = 0; n < 8; ++n)
        b[n] = *(bf16x8*)&Bl[(wc * 128 + n * 16 + l15) * LDP + k2 * 32 + l4 * 8];
#pragma unroll
      for (int f = 0; f < 2; ++f)
#pragma unroll
        for (int n = 0; n < 8; ++n)
          acc[f][n] = __builtin_amdgcn_mfma_f32_16x16x32_bf16(a[f], b[n], acc[f][n], 0, 0, 0);
    }
  }

  // epilogue: C[row=(lane>>4)*4+reg][col=lane&15] per 16x16 frag
#pragma unroll
  for (int f = 0; f < 2; ++f) {
    int mbase = m0 + wr * 32 + f * 16 + l4 * 4;
#pragma unroll
    for (int n = 0; n < 8; ++n) {
      int cl = nb + wc * 128 + n * 16 + l15;
      bool cv = (ch * CHUNK + cl) < N_TRAIN;
#pragma unroll
      for (int r = 0; r < 4; ++r) {
        int m = mbase + r;
        if (m < M_ROWS)
          simbuf[(size_t)m * CHUNK + cl] = cv ? acc[f][n][r] : -FLT_MAX;
      }
    }
  }
}

// ---------------- per-(row,chunk) exact top-K2 via radix/histogram ------------
// f32 -> order-preserving u32 key; 4096-bin histogram of key>>20 finds the bin
// holding rank K2; collect all keys >= bin floor (C ~ 24-50); rank-select.
// Identical result to serial max-extraction incl. (value desc, idx asc) ties.
__global__ __launch_bounds__(256) void select_chunk(const float* __restrict__ simbuf,
                                                    float* __restrict__ topv,
                                                    unsigned short* __restrict__ topi, int ch) {
  const int t = threadIdx.x;
  const int m = blockIdx.x;

  __shared__ unsigned int hist[4096];
  __shared__ unsigned int segsum[256];
  __shared__ unsigned int sBin, sAbove, sCnt;
  __shared__ unsigned int cnt;
  __shared__ unsigned int cKey[CAP];
  __shared__ unsigned short cIdx[CAP];

  unsigned int key[24];
#pragma unroll
  for (int i = 0; i < 24; ++i) {
    unsigned int b = __float_as_uint(simbuf[(size_t)m * CHUNK + i * 256 + t]);
    key[i] = (b & 0x80000000u) ? ~b : (b | 0x80000000u);
  }

  // ---- level 0: histogram of key>>20 ----
#pragma unroll
  for (int i = 0; i < 16; ++i) hist[i * 256 + t] = 0u;
  __syncthreads();
#pragma unroll
  for (int i = 0; i < 24; ++i) atomicAdd(&hist[key[i] >> 20], 1u);
  __syncthreads();
  {
    unsigned int seg = 0;
#pragma unroll
    for (int i = 0; i < 16; ++i) seg += hist[t * 16 + i];
    segsum[t] = seg;
    __syncthreads();
    for (int off = 1; off < 256; off <<= 1) {
      unsigned int add = (t + off < 256) ? segsum[t + off] : 0u;
      __syncthreads();
      segsum[t] += add;
      __syncthreads();
    }
    unsigned int run = (t == 255) ? 0u : segsum[t + 1];
    for (int i = 15; i >= 0; --i) {
      unsigned int h = hist[t * 16 + i];
      if (run < K2 && run + h >= K2) { sBin = (unsigned)(t * 16 + i); sAbove = run; sCnt = run + h; }
      run += h;
    }
  }
  __syncthreads();
  unsigned int p0 = sBin, above = sAbove, C = sCnt;
  unsigned int thr = p0 << 20;

  // ---- level 1 (rare): refine on bits [19:8] within bin p0 ----
  if (C > CAP) {
#pragma unroll
    for (int i = 0; i < 16; ++i) hist[i * 256 + t] = 0u;
    __syncthreads();
#pragma unroll
    for (int i = 0; i < 24; ++i)
      if ((key[i] >> 20) == p0) atomicAdd(&hist[(key[i] >> 8) & 0xFFFu], 1u);
    __syncthreads();
    unsigned int seg = 0;
#pragma unroll
    for (int i = 0; i < 16; ++i) seg += hist[t * 16 + i];
    segsum[t] = seg;
    __syncthreads();
    for (int off = 1; off < 256; off <<= 1) {
      unsigned int add = (t + off < 256) ? segsum[t + off] : 0u;
      __syncthreads();
      segsum[t] += add;
      __syncthreads();
    }
    unsigned int run = above + ((t == 255) ? 0u : segsum[t + 1]);
    for (int i = 15; i >= 0; --i) {
      unsigned int h = hist[t * 16 + i];
      if (run < K2 && run + h >= K2) { sBin = (unsigned)(t * 16 + i); sAbove = run; sCnt = run + h; }
      run += h;
    }
    __syncthreads();
    unsigned int p1 = sBin; above = sAbove; C = sCnt;
    thr = (p0 << 20) | (p1 << 8);

    // ---- level 2 (virtually never): last 8 bits ----
    if (C > CAP) {
      hist[t] = 0u;
      __syncthreads();
      unsigned int pfx = (p0 << 12) | p1;
#pragma unroll
      for (int i = 0; i < 24; ++i)
        if ((key[i] >> 8) == pfx) atomicAdd(&hist[key[i] & 0xFFu], 1u);
      __syncthreads();
      segsum[t] = hist[t];
      __syncthreads();
      for (int off = 1; off < 256; off <<= 1) {
        unsigned int add = (t + off < 256) ? segsum[t + off] : 0u;
        __syncthreads();
        segsum[t] += add;
        __syncthreads();
      }
      unsigned int runv = above + ((t == 255) ? 0u : segsum[t + 1]);
      unsigned int h = hist[t];
      if (runv < K2 && runv + h >= K2) { sBin = (unsigned)t; sCnt = runv + h; }
      __syncthreads();
      thr = (pfx << 8) | sBin;
      C = sCnt;
    }
  }

  // ---- collect all keys >= thr ----
  if (t == 0) cnt = 0u;
  __syncthreads();
#pragma unroll
  for (int i = 0; i < 24; ++i) {
    if (key[i] >= thr) {
      unsigned int pos = atomicAdd(&cnt, 1u);
      if (pos < CAP) { cKey[pos] = key[i]; cIdx[pos] = (unsigned short)(i * 256 + t); }
    }
  }
  __syncthreads();
  int Cc = (int)min(cnt, (unsigned)CAP);

  // ---- rank-select top-K2 by (key desc, idx asc) ----
  for (int s = t; s < Cc; s += 256) {
    unsigned int k = cKey[s]; unsigned short id = cIdx[s];
    int r = 0;
    for (int j = 0; j < Cc; ++j) {
      unsigned int kj = cKey[j];
      r += (kj > k || (kj == k && cIdx[j] < id)) ? 1 : 0;
    }
    if (r < K2) {
      unsigned int b = (k & 0x80000000u) ? (k & 0x7fffffffu) : ~k;
      topv[(size_t)m * NCAND + ch * K2 + r] = __uint_as_float(b);
      topi[(size_t)m * NCAND + ch * K2 + r] = id;
    }
  }
}

// ---------------- merge 216 -> top-24 candidate indices (rank-select) ---------
__global__ __launch_bounds__(256) void merge24(const float* __restrict__ topv,
                                               const unsigned short* __restrict__ topi,
                                               int* __restrict__ selIdx) {
  const int m = blockIdx.x, t = threadIdx.x;
  __shared__ float cv[NCAND];
  __shared__ int   ci[NCAND];
  if (t < NCAND) {
    cv[t] = topv[(size_t)m * NCAND + t];
    ci[t] = (t / K2) * CHUNK + (int)topi[(size_t)m * NCAND + t];
  }
  __syncthreads();
  if (t < NCAND) {
    float v = cv[t]; int id = ci[t];
    int r = 0;
    for (int n = 0; n < NCAND; ++n) {
      float nv = cv[n]; int ni = ci[n];
      r += (nv > v || (nv == v && ni < id)) ? 1 : 0;
    }
    if (r < K2) selIdx[(size_t)m * K2 + r] = id;
  }
}

// ---------------- f64 refine of 24 cands -> exact top-20 -> f64 softmax -------
__global__ __launch_bounds__(256) void refine_softmax(const int* __restrict__ selIdx,
                                                      const float* __restrict__ test,
                                                      const float* __restrict__ trainT,
                                                      double* __restrict__ wval,
                                                      int* __restrict__ widx) {
  const int m = blockIdx.x, t = threadIdx.x;
  __shared__ int    sIdx[K2];
  __shared__ double rvs[K2];
  __shared__ double sv2[K2];
  __shared__ int    si2[K2];
  __shared__ double earr[KNN];
  if (t < K2) sIdx[t] = selIdx[(size_t)m * K2 + t];
  __syncthreads();

  const int wid = t >> 6, lane = t & 63;
  float tr[DDIM / 64];
#pragma unroll
  for (int dd = 0; dd < DDIM / 64; ++dd)
    tr[dd] = test[(size_t)m * DDIM + dd * 64 + lane];
#pragma unroll 1
  for (int c = wid; c < K2; c += 4) {
    const float* Tc = trainT + (size_t)sIdx[c] * DDIM;
    double s = 0.0;
#pragma unroll
    for (int dd = 0; dd < DDIM / 64; ++dd)
      s += (double)tr[dd] * (double)Tc[dd * 64 + lane];
#pragma unroll
    for (int off = 32; off > 0; off >>= 1) s += __shfl_xor(s, off);
    if (lane == 0) rvs[c] = s;
  }
  __syncthreads();

  if (t < K2) {
    double v = rvs[t]; int id = sIdx[t];
    int r = 0;
    for (int n = 0; n < K2; ++n)
      r += (rvs[n] > v || (rvs[n] == v && sIdx[n] < id)) ? 1 : 0;
    sv2[r] = v; si2[r] = id;
  }
  __syncthreads();

  if (t < KNN) earr[t] = exp(sv2[t] - sv2[0]);
  __syncthreads();
  if (t < KNN) {
    double ssum = 0.0;
    for (int k = 0; k < KNN; ++k) ssum += earr[k];
    wval[(size_t)m * KNN + t] = earr[t] / ssum;
    widx[(size_t)m * KNN + t] = si2[t];
  }
}

// ---------------- per-pixel weighted vote (f64) + argmax ----------------------
__global__ __launch_bounds__(256) void vote_kernel(const double* __restrict__ wval,
                                                   const int* __restrict__ widx,
                                                   const unsigned char* __restrict__ labT,
                                                   int* __restrict__ out) {
  const int m = blockIdx.x, t = threadIdx.x;
  __shared__ double sw[KNN];
  __shared__ int    si[KNN];
  if (t < KNN) { sw[t] = wval[(size_t)m * KNN + t]; si[t] = widx[(size_t)m * KNN + t]; }
  __syncthreads();

  unsigned int packed[5];
#pragma unroll
  for (int q = 0; q < 5; ++q) {
    unsigned int p = 0;
#pragma unroll
    for (int j = 0; j < 4; ++j)
      p |= (unsigned int)labT[(size_t)si[q * 4 + j] * 256 + t] << (8 * j);
    packed[q] = p;
  }

  double best = -1.0; int bc = 0;
#pragma unroll 1
  for (int c = 0; c < NCLS; ++c) {
    double s = 0.0;
#pragma unroll
    for (int k = 0; k < KNN; ++k) {
      unsigned int lab = (packed[k >> 2] >> ((k & 3) * 8)) & 255u;
      s += (lab == (unsigned int)c) ? sw[k] : 0.0;
    }
    if (s > best) { best = s; bc = c; }
  }

  const int b = m / 196, p = m % 196;
  const int py = p / 14, px = p % 14;
  const int i = t >> 4, j = t & 15;
  out[((size_t)b * 224 + py * 16 + i) * 224 + px * 16 + j] = bc;
}

// ---------------- launch ------------------------------------------------------
// ws layout (bytes), total 91,917,824 (< 92,083,712 proven-safe):
//   labT    @ 0          : 12,800,000
//   simbuf  @ 12,800,000 : 38,535,168  (f32, dead after last select)
//   bhT     @ 51,335,168 : 38,400,000  (bf16, dead after last mfma_gemm)
//   trainT  @ 12,800,000 : 76,800,000  (ALIASES simbuf+bhT; written after both die)
//   topv    @ 89,735,168 :  1,354,752  (dead after merge24)
//   topi    @ 91,089,920 :    677,376  (u16; dead after merge24)
//   selIdx  @ 91,767,296 :    150,528
//   wval    @ 89,735,168 :    250,880  (reuses dead topv region)
//   widx    @ 89,986,048 :    125,440
extern "C" void kernel_launch(void* const* d_in, const int* in_sizes, int n_in,
                              void* d_out, int out_size, void* d_ws, size_t ws_size,
                              hipStream_t stream) {
  const float* test  = (const float*)d_in[0];   // [1568][384]
  const float* train = (const float*)d_in[1];   // [384][50000]
  const int* labels  = (const int*)d_in[2];     // [256][50000]
  int* out = (int*)d_out;
  char* ws = (char*)d_ws;

  unsigned char*  labT   = (unsigned char*)ws;
  float*          simbuf = (float*)(ws + 12800000);
  unsigned short* bhT    = (unsigned short*)(ws + 51335168);
  float*          trainT = (float*)(ws + 12800000);   // alias (after simbuf+bhT dead)
  float*          topv   = (float*)(ws + 89735168);
  unsigned short* topi   = (unsigned short*)(ws + 91089920);
  int*            selIdx = (int*)(ws + 91767296);
  double*         wval   = (double*)(ws + 89735168);  // reuses dead topv
  int*            widx   = (int*)(ws + 89986048);

  transpose_labels<<<dim3(782, 4), 256, 0, stream>>>(labels, labT);
  conv_bhT<<<dim3(782, 6), 256, 0, stream>>>(train, bhT);
  for (int ch = 0; ch < NCHUNKS; ++ch) {
    mfma_gemm<<<dim3(25, 24), 256, 0, stream>>>(test, bhT, simbuf, ch);
    select_chunk<<<dim3(M_ROWS), 256, 0, stream>>>(simbuf, topv, topi, ch);
  }
  merge24<<<dim3(M_ROWS), 256, 0, stream>>>(topv, topi, selIdx);
  transpose_train<<<dim3(782, 6), 256, 0, stream>>>(train, trainT);
  refine_softmax<<<dim3(M_ROWS), 256, 0, stream>>>(selIdx, test, trainT, wval, widx);
  vote_kernel<<<dim3(M_ROWS), 256, 0, stream>>>(wval, widx, labT, out);
}

// Round 7
// 423.581 us; speedup vs baseline: 5.4654x; 1.3080x over previous
//
#include <hip/hip_runtime.h>
#include <float.h>

#define N_TRAIN 50000
#define NPAD    50176        // 196*256 padded col count
#define DDIM    384
#define M_ROWS  1568         // 8*196
#define KNN     20
#define K2      24           // candidate-inclusion rank (margin over 20)
#define SELMAX  64           // max refined candidates per row
#define NCLS    21
#define CAPBUF  768

typedef __attribute__((ext_vector_type(8))) short bf16x8;
typedef __attribute__((ext_vector_type(4))) float f32x4;

// round-to-nearest-even f32 -> bf16
static __device__ __forceinline__ unsigned short f2bf(float f) {
  unsigned int u = __float_as_uint(f);
  unsigned int r = (u + 0x7fffu + ((u >> 16) & 1u)) >> 16;
  return (unsigned short)r;
}
// order-preserving f32 -> u32 key
static __device__ __forceinline__ unsigned int flip32(unsigned int u) {
  return (u & 0x80000000u) ? ~u : (u | 0x80000000u);
}

// ---------------- transpose labels [256][50000] i32 -> [50000][256] u8 --------
__global__ __launch_bounds__(256) void transpose_labels(const int* __restrict__ labels,
                                                        unsigned char* __restrict__ labT) {
  __shared__ int tile[64][65];
  const int t  = threadIdx.x;
  const int c0 = blockIdx.x * 64;
  const int r0 = blockIdx.y * 64;
#pragma unroll
  for (int i = 0; i < 16; ++i) {
    int idx = i * 256 + t;
    int r = idx >> 6, c = idx & 63;
    int cc = c0 + c;
    tile[r][c] = (cc < N_TRAIN) ? labels[(size_t)(r0 + r) * N_TRAIN + cc] : 0;
  }
  __syncthreads();
#pragma unroll
  for (int i = 0; i < 16; ++i) {
    int idx = i * 256 + t;
    int c = idx >> 6, r = idx & 63;
    int cc = c0 + c;
    if (cc < N_TRAIN) labT[(size_t)cc * 256 + r0 + r] = (unsigned char)tile[r][c];
  }
}

// ------- transpose+convert train [384][50000] f32 -> bhT [50176][384] bf16 ----
// (pad rows 50000..50175 are written as zeros)
__global__ __launch_bounds__(256) void conv_bhT(const float* __restrict__ train,
                                                unsigned short* __restrict__ bhT) {
  __shared__ float tile[64][65];
  const int t  = threadIdx.x;
  const int c0 = blockIdx.x * 64;   // col (0..50176)
  const int r0 = blockIdx.y * 64;   // k
#pragma unroll
  for (int i = 0; i < 16; ++i) {
    int idx = i * 256 + t;
    int r = idx >> 6, c = idx & 63;
    int cc = c0 + c;
    tile[r][c] = (cc < N_TRAIN) ? train[(size_t)(r0 + r) * N_TRAIN + cc] : 0.f;
  }
  __syncthreads();
#pragma unroll
  for (int i = 0; i < 16; ++i) {
    int idx = i * 256 + t;
    int c = idx >> 6, r = idx & 63;
    int cc = c0 + c;                 // < 50176 by grid construction
    bhT[(size_t)cc * DDIM + r0 + r] = f2bf(tile[r][c]);
  }
}

// ---------------- transpose train [384][50000] f32 -> [50000][384] f32 --------
__global__ __launch_bounds__(256) void transpose_train(const float* __restrict__ train,
                                                       float* __restrict__ trainT) {
  __shared__ float tile[64][65];
  const int t  = threadIdx.x;
  const int c0 = blockIdx.x * 64;
  const int r0 = blockIdx.y * 64;
#pragma unroll
  for (int i = 0; i < 16; ++i) {
    int idx = i * 256 + t;
    int r = idx >> 6, c = idx & 63;
    int cc = c0 + c;
    tile[r][c] = (cc < N_TRAIN) ? train[(size_t)(r0 + r) * N_TRAIN + cc] : 0.f;
  }
  __syncthreads();
#pragma unroll
  for (int i = 0; i < 16; ++i) {
    int idx = i * 256 + t;
    int c = idx >> 6, r = idx & 63;
    int cc = c0 + c;
    if (cc < N_TRAIN) trainT[(size_t)cc * DDIM + r0 + r] = tile[r][c];
  }
}

// ---------------- MFMA bf16 GEMM (full N): keybuf[m][c] = key16(sim) ----------
// block tile 128m x 256n, 4 waves (2x2), wave tile 64x128, K_STEP=64.
#define BMT 128
#define BNT 256
#define KST 64
#define LDP 72   // LDS row stride in bf16 units (144 B: 16B-aligned, bank-friendly)

__global__ __launch_bounds__(256) void mfma_gemm(const float* __restrict__ test,
                                                 const unsigned short* __restrict__ bhT,
                                                 unsigned short* __restrict__ keybuf) {
  __shared__ unsigned short Al[BMT * LDP];   // 18,432 B
  __shared__ unsigned short Bl[BNT * LDP];   // 36,864 B
  const int t  = threadIdx.x;
  const int m0 = blockIdx.x * BMT;
  const int nb = blockIdx.y * BNT;           // global col base (max 49,920)

  const int wid = t >> 6, lane = t & 63;
  const int wr = wid >> 1, wc = wid & 1;
  const int l15 = lane & 15, l4 = lane >> 4;

  f32x4 acc[4][8];
  const f32x4 zero = {0.f, 0.f, 0.f, 0.f};
#pragma unroll
  for (int f = 0; f < 4; ++f)
#pragma unroll
    for (int n = 0; n < 8; ++n) acc[f][n] = zero;

  for (int ks = 0; ks < DDIM / KST; ++ks) {
    __syncthreads();
    // stage A: 128 rows x 64 k from f32 test (convert in-reg)
#pragma unroll
    for (int p = 0; p < 8; ++p) {
      int flat = p * 256 + t;
      int r = flat >> 4, q = flat & 15;
      int mm = m0 + r; if (mm > M_ROWS - 1) mm = M_ROWS - 1;
      float4 v = *(const float4*)&test[(size_t)mm * DDIM + ks * KST + q * 4];
      ushort4 h;
      h.x = f2bf(v.x); h.y = f2bf(v.y); h.z = f2bf(v.z); h.w = f2bf(v.w);
      *(ushort4*)&Al[r * LDP + q * 4] = h;
    }
    // stage B: 256 n x 64 k direct bf16 16B chunks from bhT [n][k]
#pragma unroll
    for (int p = 0; p < 8; ++p) {
      int flat = p * 256 + t;
      int n = flat >> 3, kq = flat & 7;
      uint4 v = *(const uint4*)&bhT[(size_t)(nb + n) * DDIM + ks * KST + kq * 8];
      *(uint4*)&Bl[n * LDP + kq * 8] = v;
    }
    __syncthreads();
#pragma unroll
    for (int k2 = 0; k2 < 2; ++k2) {
      bf16x8 a[4], b[8];
#pragma unroll
      for (int f = 0; f < 4; ++f)
        a[f] = *(bf16x8*)&Al[(wr * 64 + f * 16 + l15) * LDP + k2 * 32 + l4 * 8];
#pragma unroll
      for (int n = 0; n < 8; ++n)
        b[n] = *(bf16x8*)&Bl[(wc * 128 + n * 16 + l15) * LDP + k2 * 32 + l4 * 8];
#pragma unroll
      for (int f = 0; f < 4; ++f)
#pragma unroll
        for (int n = 0; n < 8; ++n)
          acc[f][n] = __builtin_amdgcn_mfma_f32_16x16x32_bf16(a[f], b[n], acc[f][n], 0, 0, 0);
    }
  }

  // epilogue: C[row=(lane>>4)*4+reg][col=lane&15] per 16x16 frag -> u16 keys
#pragma unroll
  for (int f = 0; f < 4; ++f) {
    int mbase = m0 + wr * 64 + f * 16 + l4 * 4;
#pragma unroll
    for (int n = 0; n < 8; ++n) {
      int cl = nb + wc * 128 + n * 16 + l15;
      bool cv = cl < N_TRAIN;
#pragma unroll
      for (int r = 0; r < 4; ++r) {
        int m = mbase + r;
        if (m < M_ROWS) {
          unsigned int kf = flip32(__float_as_uint(acc[f][n][r]));
          keybuf[(size_t)m * NPAD + cl] = cv ? (unsigned short)(kf >> 16) : 0;
        }
      }
    }
  }
}

// ---------------- global exact candidate selection (one dispatch) -------------
// Per row: tauA = 24th-largest of per-thread maxima (<= true 24th by subset
// argument) -> collect all keys >= tauA (C ~25-60, superset of exact top-24)
// -> rank by (key desc, col asc) -> keep all with key >= key(rank 23).
__global__ __launch_bounds__(256) void select_all(const unsigned short* __restrict__ keybuf,
                                                  int* __restrict__ selCols,
                                                  int* __restrict__ selCnt) {
  const int t = threadIdx.x, m = blockIdx.x;
  __shared__ unsigned int smax[256];
  __shared__ unsigned int sbuf[CAPBUF];
  __shared__ short        srk[CAPBUF];
  __shared__ unsigned int scnt, sTauA, sTau;
  __shared__ int sC2;

  const unsigned int* kp = (const unsigned int*)(keybuf + (size_t)m * NPAD);
  unsigned int kv[98];
#pragma unroll
  for (int i = 0; i < 98; ++i) kv[i] = kp[i * 256 + t];

  unsigned int mx = 0;
#pragma unroll
  for (int i = 0; i < 98; ++i) {
    unsigned int lo = kv[i] & 0xFFFFu, hi = kv[i] >> 16;
    unsigned int h = lo > hi ? lo : hi;
    mx = h > mx ? h : mx;
  }
  if (t == 0) { scnt = 0u; sC2 = 0; }
  smax[t] = (mx << 8) | (unsigned int)(255 - t);   // (max desc, tid asc) unique
  __syncthreads();

  unsigned int myc = smax[t];
  int rnk = 0;
  for (int j = 0; j < 256; ++j) rnk += (smax[j] > myc) ? 1 : 0;
  if (rnk == K2 - 1) sTauA = myc >> 8;
  __syncthreads();
  const unsigned int tauA = sTauA;

  // collect entries (key<<16)|(0xFFFF-col): desc order == (key desc, col asc)
#pragma unroll
  for (int i = 0; i < 98; ++i) {
    unsigned int lo = kv[i] & 0xFFFFu, hi = kv[i] >> 16;
    int colb = i * 512 + 2 * t;
    if (lo >= tauA) {
      unsigned int p = atomicAdd(&scnt, 1u);
      if (p < CAPBUF) sbuf[p] = (lo << 16) | (unsigned int)(0xFFFF - colb);
    }
    if (hi >= tauA) {
      unsigned int p = atomicAdd(&scnt, 1u);
      if (p < CAPBUF) sbuf[p] = (hi << 16) | (unsigned int)(0xFFFF - (colb + 1));
    }
  }
  __syncthreads();
  const int C = (int)min(scnt, (unsigned int)CAPBUF);   // C >= 24 guaranteed

  for (int s = t; s < C; s += 256) {
    unsigned int e = sbuf[s];
    int rk = 0;
    for (int j = 0; j < C; ++j) rk += (sbuf[j] > e) ? 1 : 0;
    srk[s] = (short)rk;
    if (rk == K2 - 1) sTau = e >> 16;
  }
  __syncthreads();
  const unsigned int tau = sTau;
  for (int s = t; s < C; s += 256) {
    unsigned int e = sbuf[s];
    int rk = (int)srk[s];
    if ((e >> 16) >= tau && rk < SELMAX) {   // prefix of desc order -> ranks 0..C2-1
      selCols[(size_t)m * SELMAX + rk] = 0xFFFF - (int)(e & 0xFFFFu);
      atomicMax(&sC2, rk + 1);
    }
  }
  __syncthreads();
  if (t == 0) selCnt[m] = sC2 < SELMAX ? sC2 : SELMAX;
}

// ---------------- f64 refine of <=64 cands -> exact top-20 -> f64 softmax -----
__global__ __launch_bounds__(256) void refine_softmax(const int* __restrict__ selCols,
                                                      const int* __restrict__ selCnt,
                                                      const float* __restrict__ test,
                                                      const float* __restrict__ trainT,
                                                      double* __restrict__ wval,
                                                      int* __restrict__ widx) {
  const int m = blockIdx.x, t = threadIdx.x;
  __shared__ int    sIdx[SELMAX];
  __shared__ double rvs[SELMAX];
  __shared__ double sv2[SELMAX];
  __shared__ int    si2[SELMAX];
  __shared__ double earr[KNN];
  const int C2 = selCnt[m];                 // 24 <= C2 <= 64
  if (t < C2) sIdx[t] = selCols[(size_t)m * SELMAX + t];
  __syncthreads();

  const int wid = t >> 6, lane = t & 63;
  float tr[DDIM / 64];
#pragma unroll
  for (int dd = 0; dd < DDIM / 64; ++dd)
    tr[dd] = test[(size_t)m * DDIM + dd * 64 + lane];
#pragma unroll 1
  for (int c = wid; c < C2; c += 4) {
    const float* Tc = trainT + (size_t)sIdx[c] * DDIM;
    double s = 0.0;
#pragma unroll
    for (int dd = 0; dd < DDIM / 64; ++dd)
      s += (double)tr[dd] * (double)Tc[dd * 64 + lane];
#pragma unroll
    for (int off = 32; off > 0; off >>= 1) s += __shfl_xor(s, off);
    if (lane == 0) rvs[c] = s;
  }
  __syncthreads();

  if (t < C2) {
    double v = rvs[t]; int id = sIdx[t];
    int r = 0;
    for (int n = 0; n < C2; ++n)
      r += (rvs[n] > v || (rvs[n] == v && sIdx[n] < id)) ? 1 : 0;
    sv2[r] = v; si2[r] = id;
  }
  __syncthreads();

  if (t < KNN) earr[t] = exp(sv2[t] - sv2[0]);
  __syncthreads();
  if (t < KNN) {
    double ssum = 0.0;
    for (int k = 0; k < KNN; ++k) ssum += earr[k];
    wval[(size_t)m * KNN + t] = earr[t] / ssum;
    widx[(size_t)m * KNN + t] = si2[t];
  }
}

// ---------------- per-pixel weighted vote (f64) + argmax ----------------------
__global__ __launch_bounds__(256) void vote_kernel(const double* __restrict__ wval,
                                                   const int* __restrict__ widx,
                                                   const unsigned char* __restrict__ labT,
                                                   int* __restrict__ out) {
  const int m = blockIdx.x, t = threadIdx.x;
  __shared__ double sw[KNN];
  __shared__ int    si[KNN];
  if (t < KNN) { sw[t] = wval[(size_t)m * KNN + t]; si[t] = widx[(size_t)m * KNN + t]; }
  __syncthreads();

  unsigned int packed[5];
#pragma unroll
  for (int q = 0; q < 5; ++q) {
    unsigned int p = 0;
#pragma unroll
    for (int j = 0; j < 4; ++j)
      p |= (unsigned int)labT[(size_t)si[q * 4 + j] * 256 + t] << (8 * j);
    packed[q] = p;
  }

  double best = -1.0; int bc = 0;
#pragma unroll 1
  for (int c = 0; c < NCLS; ++c) {
    double s = 0.0;
#pragma unroll
    for (int k = 0; k < KNN; ++k) {
      unsigned int lab = (packed[k >> 2] >> ((k & 3) * 8)) & 255u;
      s += (lab == (unsigned int)c) ? sw[k] : 0.0;
    }
    if (s > best) { best = s; bc = c; }
  }

  const int b = m / 196, p = m % 196;
  const int py = p / 14, px = p % 14;
  const int i = t >> 4, j = t & 15;
  out[((size_t)b * 224 + py * 16 + i) * 224 + px * 16 + j] = bc;
}

// ---------------- launch ------------------------------------------------------
// ws layout (bytes), total 209,471,104 (ws_size ~= 307.2 MB per harness poison):
//   labT    @ 0           : 12,800,000
//   bhT     @ 12,800,000  : 38,535,168  (u16 [50176][384], dead after gemm)
//   keybuf  @ 51,335,168  : 157,351,936 (u16 [1568][50176], dead after select)
//   trainT  @ 51,335,168  : 76,800,000  (ALIASES keybuf; written after it dies)
//   selCols @ 208,687,104 :    401,408  (int [1568][64])
//   selCnt  @ 209,088,512 :      6,272
//   wval    @ 209,094,784 :    250,880
//   widx    @ 209,345,664 :    125,440
extern "C" void kernel_launch(void* const* d_in, const int* in_sizes, int n_in,
                              void* d_out, int out_size, void* d_ws, size_t ws_size,
                              hipStream_t stream) {
  const float* test  = (const float*)d_in[0];   // [1568][384]
  const float* train = (const float*)d_in[1];   // [384][50000]
  const int* labels  = (const int*)d_in[2];     // [256][50000]
  int* out = (int*)d_out;
  char* ws = (char*)d_ws;

  unsigned char*  labT    = (unsigned char*)ws;
  unsigned short* bhT     = (unsigned short*)(ws + 12800000);
  unsigned short* keybuf  = (unsigned short*)(ws + 51335168);
  float*          trainT  = (float*)(ws + 51335168);   // temporal alias of keybuf
  int*            selCols = (int*)(ws + 208687104);
  int*            selCnt  = (int*)(ws + 209088512);
  double*         wval    = (double*)(ws + 209094784);
  int*            widx    = (int*)(ws + 209345664);

  transpose_labels<<<dim3(782, 4), 256, 0, stream>>>(labels, labT);
  conv_bhT<<<dim3(784, 6), 256, 0, stream>>>(train, bhT);
  mfma_gemm<<<dim3(13, 196), 256, 0, stream>>>(test, bhT, keybuf);
  select_all<<<dim3(M_ROWS), 256, 0, stream>>>(keybuf, selCols, selCnt);
  transpose_train<<<dim3(782, 6), 256, 0, stream>>>(train, trainT);
  refine_softmax<<<dim3(M_ROWS), 256, 0, stream>>>(selCols, selCnt, test, trainT, wval, widx);
  vote_kernel<<<dim3(M_ROWS), 256, 0, stream>>>(wval, widx, labT, out);
}

// Round 8
// 284.583 us; speedup vs baseline: 8.1349x; 1.4884x over previous
//
#include <hip/hip_runtime.h>
#include <float.h>

#define N_TRAIN 50000
#define NPAD    50176        // 392*128 padded col count
#define NBLK    392          // 128-col blocks
#define MPAD    1664         // 13*128 padded row count
#define DDIM    384
#define M_ROWS  1568         // 8*196
#define KNN     20
#define K2      24           // candidate-inclusion rank (margin over 20)
#define SELMAX  64           // max refined candidates per row
#define NCLS    21
#define CAPBUF  768
#define CBMAX   256

typedef __attribute__((ext_vector_type(8))) short bf16x8;
typedef __attribute__((ext_vector_type(4))) float f32x4;

#define GLOAD_LDS16(gp, lp) \
  __builtin_amdgcn_global_load_lds((const __attribute__((address_space(1))) void*)(gp), \
                                   (__attribute__((address_space(3))) void*)(lp), 16, 0, 0)

// round-to-nearest-even f32 -> bf16
static __device__ __forceinline__ unsigned short f2bf(float f) {
  unsigned int u = __float_as_uint(f);
  unsigned int r = (u + 0x7fffu + ((u >> 16) & 1u)) >> 16;
  return (unsigned short)r;
}
// order-preserving f32 -> u32 key
static __device__ __forceinline__ unsigned int flip32(unsigned int u) {
  return (u & 0x80000000u) ? ~u : (u | 0x80000000u);
}

// ---------------- transpose labels [256][50000] i32 -> [50000][256] u8 --------
__global__ __launch_bounds__(256) void transpose_labels(const int* __restrict__ labels,
                                                        unsigned char* __restrict__ labT) {
  __shared__ int tile[64][65];
  const int t  = threadIdx.x;
  const int c0 = blockIdx.x * 64;
  const int r0 = blockIdx.y * 64;
#pragma unroll
  for (int i = 0; i < 16; ++i) {
    int idx = i * 256 + t;
    int r = idx >> 6, c = idx & 63;
    int cc = c0 + c;
    tile[r][c] = (cc < N_TRAIN) ? labels[(size_t)(r0 + r) * N_TRAIN + cc] : 0;
  }
  __syncthreads();
#pragma unroll
  for (int i = 0; i < 16; ++i) {
    int idx = i * 256 + t;
    int c = idx >> 6, r = idx & 63;
    int cc = c0 + c;
    if (cc < N_TRAIN) labT[(size_t)cc * 256 + r0 + r] = (unsigned char)tile[r][c];
  }
}

// ---------------- convert test [1568][384] f32 -> bf16A [1664][384] (pad 0) ---
__global__ __launch_bounds__(256) void conv_bf16A(const float* __restrict__ test,
                                                  unsigned short* __restrict__ bf16A) {
  int idx = blockIdx.x * 256 + threadIdx.x;      // over MPAD*DDIM = 638,976
  if (idx >= MPAD * DDIM) return;
  int row = idx / DDIM;
  bf16A[idx] = (row < M_ROWS) ? f2bf(test[idx]) : (unsigned short)0;
}

// ------- transpose+convert train [384][50000] f32 -> bhT [50176][384] bf16 ----
__global__ __launch_bounds__(256) void conv_bhT(const float* __restrict__ train,
                                                unsigned short* __restrict__ bhT) {
  __shared__ float tile[64][65];
  const int t  = threadIdx.x;
  const int c0 = blockIdx.x * 64;   // col (0..50176)
  const int r0 = blockIdx.y * 64;   // k
#pragma unroll
  for (int i = 0; i < 16; ++i) {
    int idx = i * 256 + t;
    int r = idx >> 6, c = idx & 63;
    int cc = c0 + c;
    tile[r][c] = (cc < N_TRAIN) ? train[(size_t)(r0 + r) * N_TRAIN + cc] : 0.f;
  }
  __syncthreads();
#pragma unroll
  for (int i = 0; i < 16; ++i) {
    int idx = i * 256 + t;
    int c = idx >> 6, r = idx & 63;
    int cc = c0 + c;                 // < 50176 by grid construction
    bhT[(size_t)cc * DDIM + r0 + r] = f2bf(tile[r][c]);
  }
}

// ---------------- transpose train [384][50000] f32 -> [50000][384] f32 --------
__global__ __launch_bounds__(256) void transpose_train(const float* __restrict__ train,
                                                       float* __restrict__ trainT) {
  __shared__ float tile[64][65];
  const int t  = threadIdx.x;
  const int c0 = blockIdx.x * 64;
  const int r0 = blockIdx.y * 64;
#pragma unroll
  for (int i = 0; i < 16; ++i) {
    int idx = i * 256 + t;
    int r = idx >> 6, c = idx & 63;
    int cc = c0 + c;
    tile[r][c] = (cc < N_TRAIN) ? train[(size_t)(r0 + r) * N_TRAIN + cc] : 0.f;
  }
  __syncthreads();
#pragma unroll
  for (int i = 0; i < 16; ++i) {
    int idx = i * 256 + t;
    int c = idx >> 6, r = idx & 63;
    int cc = c0 + c;
    if (cc < N_TRAIN) trainT[(size_t)cc * DDIM + r0 + r] = tile[r][c];
  }
}

// ---------------- MFMA bf16 GEMM (m97-style): keys + per-block row-max --------
// 128x128 tile, 4 waves 2x2 (wave 64x64), BK=64. Both operands K-major bf16,
// staged with global_load_lds(16B) into linear LDS with pre-swizzled source;
// reads apply the same XOR -> bank-conflict-light ds_read_b128.
__global__ __launch_bounds__(256) void mfma_gemm(const unsigned short* __restrict__ bf16A,
                                                 const unsigned short* __restrict__ bhT,
                                                 unsigned short* __restrict__ keybuf,
                                                 unsigned short* __restrict__ blkmax) {
  __shared__ unsigned short Al[128 * 64];   // 16 KB, linear [row][64]
  __shared__ unsigned short Bl[128 * 64];   // 16 KB
  __shared__ unsigned int rowmax[128];
  const int t = threadIdx.x;

  // bijective XCD-chunked swizzle: 5096 = 8 * 637; same-n m-blocks -> same XCD
  const int flat = blockIdx.x;
  const int wrk  = (flat & 7) * 637 + (flat >> 3);
  const int nblk = wrk / 13, mblk = wrk % 13;
  const int m0 = mblk * 128, n0 = nblk * 128;

  if (t < 128) rowmax[t] = 0u;

  const int wid = t >> 6, lane = t & 63;
  const int wr = wid >> 1, wc = wid & 1;
  const int l15 = lane & 15, l4 = lane >> 4;
  const int srow  = lane >> 3;                  // row-in-segment 0..7
  const int sslot = (lane & 7) ^ srow;          // pre-swizzled source k-slot

  f32x4 acc[4][4];
  const f32x4 zero = {0.f, 0.f, 0.f, 0.f};
#pragma unroll
  for (int f = 0; f < 4; ++f)
#pragma unroll
    for (int n = 0; n < 4; ++n) acc[f][n] = zero;

  for (int ks = 0; ks < DDIM / 64; ++ks) {
    __syncthreads();   // previous LDS reads done (also covers rowmax init)
#pragma unroll
    for (int j = 0; j < 4; ++j) {
      int seg  = wid * 4 + j;                    // 16 segments of 1024 B
      int arow = seg * 8 + srow;
      GLOAD_LDS16(bf16A + (size_t)(m0 + arow) * DDIM + ks * 64 + sslot * 8,
                  &Al[seg * 512]);
      GLOAD_LDS16(bhT + (size_t)(n0 + arow) * DDIM + ks * 64 + sslot * 8,
                  &Bl[seg * 512]);
    }
    __syncthreads();   // compiler drains vmcnt before barrier
#pragma unroll
    for (int k2 = 0; k2 < 2; ++k2) {
      bf16x8 a[4], b[4];
#pragma unroll
      for (int f = 0; f < 4; ++f) {
        int row = wr * 64 + f * 16 + l15;
        int kel = (k2 * 32 + l4 * 8) ^ ((row & 7) << 3);
        a[f] = *(bf16x8*)&Al[row * 64 + kel];
      }
#pragma unroll
      for (int n = 0; n < 4; ++n) {
        int row = wc * 64 + n * 16 + l15;
        int kel = (k2 * 32 + l4 * 8) ^ ((row & 7) << 3);
        b[n] = *(bf16x8*)&Bl[row * 64 + kel];
      }
#pragma unroll
      for (int f = 0; f < 4; ++f)
#pragma unroll
        for (int n = 0; n < 4; ++n)
          acc[f][n] = __builtin_amdgcn_mfma_f32_16x16x32_bf16(a[f], b[n], acc[f][n], 0, 0, 0);
    }
  }

  // epilogue: u16 keys + per-row block max
  unsigned int rmax[4][4];
#pragma unroll
  for (int f = 0; f < 4; ++f)
#pragma unroll
    for (int r = 0; r < 4; ++r) rmax[f][r] = 0u;

#pragma unroll
  for (int f = 0; f < 4; ++f) {
    const int mrow0 = m0 + wr * 64 + f * 16 + l4 * 4;
#pragma unroll
    for (int n = 0; n < 4; ++n) {
      const int col = n0 + wc * 64 + n * 16 + l15;
      const bool cv = col < N_TRAIN;
#pragma unroll
      for (int r = 0; r < 4; ++r) {
        unsigned int k16 = cv ? (flip32(__float_as_uint(acc[f][n][r])) >> 16) : 0u;
        if (mrow0 + r < M_ROWS)
          keybuf[(size_t)(mrow0 + r) * NPAD + col] = (unsigned short)k16;
        if (k16 > rmax[f][r]) rmax[f][r] = k16;
      }
    }
  }
#pragma unroll
  for (int f = 0; f < 4; ++f)
#pragma unroll
    for (int r = 0; r < 4; ++r) {
      unsigned int v = rmax[f][r];
      v = max(v, (unsigned int)__shfl_xor((int)v, 1));
      v = max(v, (unsigned int)__shfl_xor((int)v, 2));
      v = max(v, (unsigned int)__shfl_xor((int)v, 4));
      v = max(v, (unsigned int)__shfl_xor((int)v, 8));
      if (l15 == 0) atomicMax(&rowmax[wr * 64 + f * 16 + l4 * 4 + r], v);
    }
  __syncthreads();
  if (t < 128) blkmax[(size_t)(m0 + t) * NBLK + nblk] = (unsigned short)rowmax[t];
}

// ---------------- exact candidate selection from block-maxes ------------------
// tauA over 392 block maxima: all true top-24 elements live in blocks whose max
// has strict-greater-rank < 24 (subset argument). Scan only those ~24 blocks'
// keys; per-thread-max threshold tauB; collect >= tauB; rank-select prefix.
__global__ __launch_bounds__(256) void select_all(const unsigned short* __restrict__ keybuf,
                                                  const unsigned short* __restrict__ blkmax,
                                                  int* __restrict__ selCols,
                                                  int* __restrict__ selCnt) {
  const int t = threadIdx.x, m = blockIdx.x;
  __shared__ unsigned short bm[NBLK];
  __shared__ int clist[CBMAX];
  __shared__ int ccnt;
  __shared__ unsigned int smax[256];
  __shared__ unsigned int sbuf[CAPBUF];
  __shared__ short srk[CAPBUF];
  __shared__ unsigned int scnt, sTauA, sTau;
  __shared__ int sC2;

  if (t == 0) { ccnt = 0; scnt = 0u; sC2 = 0; }
  for (int i = t; i < NBLK; i += 256) bm[i] = blkmax[(size_t)m * NBLK + i];
  __syncthreads();

  // candidate blocks: strict-greater-rank < K2 (includes all ties: superset)
  for (int i = t; i < NBLK; i += 256) {
    unsigned short v = bm[i];
    int cgt = 0;
    for (int j = 0; j < NBLK; ++j) cgt += (bm[j] > v) ? 1 : 0;
    if (cgt < K2) { int p = atomicAdd(&ccnt, 1); if (p < CBMAX) clist[p] = i; }
  }
  __syncthreads();
  const int CB = min(ccnt, CBMAX);
  const int TOT = CB * 128;

  // per-thread max over candidate-block keys
  unsigned int tmx = 0u;
  for (int i = t; i < TOT; i += 256) {
    int col = clist[i >> 7] * 128 + (i & 127);
    unsigned int k = keybuf[(size_t)m * NPAD + col];
    if (k > tmx) tmx = k;
  }
  smax[t] = (tmx << 8) | (unsigned int)(255 - t);
  __syncthreads();
  {
    unsigned int myc = smax[t];
    int rnk = 0;
    for (int j = 0; j < 256; ++j) rnk += (smax[j] > myc) ? 1 : 0;
    if (rnk == K2 - 1) sTauA = myc >> 8;
  }
  __syncthreads();
  const unsigned int tauB = sTauA;

  // collect all candidate keys >= tauB (guaranteed superset of exact top-24)
  for (int i = t; i < TOT; i += 256) {
    int col = clist[i >> 7] * 128 + (i & 127);
    unsigned int k = keybuf[(size_t)m * NPAD + col];
    if (k >= tauB) {
      unsigned int p = atomicAdd(&scnt, 1u);
      if (p < CAPBUF) sbuf[p] = (k << 16) | (unsigned int)(0xFFFF - col);
    }
  }
  __syncthreads();
  const int C = (int)min(scnt, (unsigned int)CAPBUF);

  for (int s = t; s < C; s += 256) {
    unsigned int e = sbuf[s];
    int rk = 0;
    for (int j = 0; j < C; ++j) rk += (sbuf[j] > e) ? 1 : 0;
    srk[s] = (short)rk;
    if (rk == K2 - 1) sTau = e >> 16;
  }
  __syncthreads();
  const unsigned int tau = sTau;
  for (int s = t; s < C; s += 256) {
    unsigned int e = sbuf[s];
    int rk = (int)srk[s];
    if ((e >> 16) >= tau && rk < SELMAX) {
      selCols[(size_t)m * SELMAX + rk] = 0xFFFF - (int)(e & 0xFFFFu);
      atomicMax(&sC2, rk + 1);
    }
  }
  __syncthreads();
  if (t == 0) selCnt[m] = sC2 < SELMAX ? sC2 : SELMAX;
}

// ---------------- f64 refine of <=64 cands -> exact top-20 -> f64 softmax -----
__global__ __launch_bounds__(256) void refine_softmax(const int* __restrict__ selCols,
                                                      const int* __restrict__ selCnt,
                                                      const float* __restrict__ test,
                                                      const float* __restrict__ trainT,
                                                      double* __restrict__ wval,
                                                      int* __restrict__ widx) {
  const int m = blockIdx.x, t = threadIdx.x;
  __shared__ int    sIdx[SELMAX];
  __shared__ double rvs[SELMAX];
  __shared__ double sv2[SELMAX];
  __shared__ int    si2[SELMAX];
  __shared__ double earr[KNN];
  const int C2 = selCnt[m];                 // 24 <= C2 <= 64
  if (t < C2) sIdx[t] = selCols[(size_t)m * SELMAX + t];
  __syncthreads();

  const int wid = t >> 6, lane = t & 63;
  float tr[DDIM / 64];
#pragma unroll
  for (int dd = 0; dd < DDIM / 64; ++dd)
    tr[dd] = test[(size_t)m * DDIM + dd * 64 + lane];
#pragma unroll 1
  for (int c = wid; c < C2; c += 4) {
    const float* Tc = trainT + (size_t)sIdx[c] * DDIM;
    double s = 0.0;
#pragma unroll
    for (int dd = 0; dd < DDIM / 64; ++dd)
      s += (double)tr[dd] * (double)Tc[dd * 64 + lane];
#pragma unroll
    for (int off = 32; off > 0; off >>= 1) s += __shfl_xor(s, off);
    if (lane == 0) rvs[c] = s;
  }
  __syncthreads();

  if (t < C2) {
    double v = rvs[t]; int id = sIdx[t];
    int r = 0;
    for (int n = 0; n < C2; ++n)
      r += (rvs[n] > v || (rvs[n] == v && sIdx[n] < id)) ? 1 : 0;
    sv2[r] = v; si2[r] = id;
  }
  __syncthreads();

  if (t < KNN) earr[t] = exp(sv2[t] - sv2[0]);
  __syncthreads();
  if (t < KNN) {
    double ssum = 0.0;
    for (int k = 0; k < KNN; ++k) ssum += earr[k];
    wval[(size_t)m * KNN + t] = earr[t] / ssum;
    widx[(size_t)m * KNN + t] = si2[t];
  }
}

// ---------------- per-pixel weighted vote (f64) + argmax ----------------------
__global__ __launch_bounds__(256) void vote_kernel(const double* __restrict__ wval,
                                                   const int* __restrict__ widx,
                                                   const unsigned char* __restrict__ labT,
                                                   int* __restrict__ out) {
  const int m = blockIdx.x, t = threadIdx.x;
  __shared__ double sw[KNN];
  __shared__ int    si[KNN];
  if (t < KNN) { sw[t] = wval[(size_t)m * KNN + t]; si[t] = widx[(size_t)m * KNN + t]; }
  __syncthreads();

  unsigned int packed[5];
#pragma unroll
  for (int q = 0; q < 5; ++q) {
    unsigned int p = 0;
#pragma unroll
    for (int j = 0; j < 4; ++j)
      p |= (unsigned int)labT[(size_t)si[q * 4 + j] * 256 + t] << (8 * j);
    packed[q] = p;
  }

  double best = -1.0; int bc = 0;
#pragma unroll 1
  for (int c = 0; c < NCLS; ++c) {
    double s = 0.0;
#pragma unroll
    for (int k = 0; k < KNN; ++k) {
      unsigned int lab = (packed[k >> 2] >> ((k & 3) * 8)) & 255u;
      s += (lab == (unsigned int)c) ? sw[k] : 0.0;
    }
    if (s > best) { best = s; bc = c; }
  }

  const int b = m / 196, p = m % 196;
  const int py = p / 14, px = p % 14;
  const int i = t >> 4, j = t & 15;
  out[((size_t)b * 224 + py * 16 + i) * 224 + px * 16 + j] = bc;
}

// ---------------- launch ------------------------------------------------------
// ws layout (bytes), total ~212.1 MB (ws ~= 307 MB per harness poison size):
//   labT    @ 0           : 12,800,000
//   bf16A   @ 12,800,000  :  1,277,952  (u16 [1664][384])
//   bhT     @ 14,077,952  : 38,535,168  (u16 [50176][384], dead after gemm)
//   keybuf  @ 52,613,120  : 157,351,936 (u16 [1568][50176], dead after select)
//   trainT  @ 52,613,120  : 76,800,000  (ALIASES keybuf; written after it dies)
//   blkmax  @ 209,965,056 :  1,304,576  (u16 [1664][392])
//   selCols @ 211,269,632 :    401,408
//   selCnt  @ 211,671,040 :      6,272
//   wval    @ 211,677,312 :    250,880
//   widx    @ 211,928,192 :    125,440
extern "C" void kernel_launch(void* const* d_in, const int* in_sizes, int n_in,
                              void* d_out, int out_size, void* d_ws, size_t ws_size,
                              hipStream_t stream) {
  const float* test  = (const float*)d_in[0];   // [1568][384]
  const float* train = (const float*)d_in[1];   // [384][50000]
  const int* labels  = (const int*)d_in[2];     // [256][50000]
  int* out = (int*)d_out;
  char* ws = (char*)d_ws;

  unsigned char*  labT    = (unsigned char*)ws;
  unsigned short* bf16A   = (unsigned short*)(ws + 12800000);
  unsigned short* bhT     = (unsigned short*)(ws + 14077952);
  unsigned short* keybuf  = (unsigned short*)(ws + 52613120);
  float*          trainT  = (float*)(ws + 52613120);   // temporal alias of keybuf
  unsigned short* blkmax  = (unsigned short*)(ws + 209965056);
  int*            selCols = (int*)(ws + 211269632);
  int*            selCnt  = (int*)(ws + 211671040);
  double*         wval    = (double*)(ws + 211677312);
  int*            widx    = (int*)(ws + 211928192);

  transpose_labels<<<dim3(782, 4), 256, 0, stream>>>(labels, labT);
  conv_bf16A<<<dim3((MPAD * DDIM + 255) / 256), 256, 0, stream>>>(test, bf16A);
  conv_bhT<<<dim3(784, 6), 256, 0, stream>>>(train, bhT);
  mfma_gemm<<<dim3(13 * NBLK), 256, 0, stream>>>(bf16A, bhT, keybuf, blkmax);
  select_all<<<dim3(M_ROWS), 256, 0, stream>>>(keybuf, blkmax, selCols, selCnt);
  transpose_train<<<dim3(782, 6), 256, 0, stream>>>(train, trainT);
  refine_softmax<<<dim3(M_ROWS), 256, 0, stream>>>(selCols, selCnt, test, trainT, wval, widx);
  vote_kernel<<<dim3(M_ROWS), 256, 0, stream>>>(wval, widx, labT, out);
}

// Round 9
// 259.762 us; speedup vs baseline: 8.9121x; 1.0955x over previous
//
#include <hip/hip_runtime.h>
#include <float.h>

#define N_TRAIN 50000
#define NPAD    50176        // 392*128 padded col count
#define NBLK    392          // 128-col blocks
#define MPAD    1664         // 13*128 padded row count
#define DDIM    384
#define M_ROWS  1568         // 8*196
#define KNN     20
#define K2      24           // candidate-inclusion rank (margin over 20)
#define SELMAX  64           // max refined candidates per row
#define NCLS    21
#define CAPBUF  768
#define CBMAX   256

typedef __attribute__((ext_vector_type(8))) short bf16x8;
typedef __attribute__((ext_vector_type(4))) float f32x4;

#define GLOAD_LDS16(gp, lp) \
  __builtin_amdgcn_global_load_lds((const __attribute__((address_space(1))) void*)(gp), \
                                   (__attribute__((address_space(3))) void*)(lp), 16, 0, 0)

// round-to-nearest-even f32 -> bf16
static __device__ __forceinline__ unsigned short f2bf(float f) {
  unsigned int u = __float_as_uint(f);
  unsigned int r = (u + 0x7fffu + ((u >> 16) & 1u)) >> 16;
  return (unsigned short)r;
}
// order-preserving f32 -> u32 key
static __device__ __forceinline__ unsigned int flip32(unsigned int u) {
  return (u & 0x80000000u) ? ~u : (u | 0x80000000u);
}

// ---------------- transpose labels [256][50000] i32 -> [50000][256] u8 --------
__global__ __launch_bounds__(256) void transpose_labels(const int* __restrict__ labels,
                                                        unsigned char* __restrict__ labT) {
  __shared__ int tile[64][65];
  const int t  = threadIdx.x;
  const int c0 = blockIdx.x * 64;
  const int r0 = blockIdx.y * 64;
#pragma unroll
  for (int i = 0; i < 16; ++i) {
    int idx = i * 256 + t;
    int r = idx >> 6, c = idx & 63;
    int cc = c0 + c;
    tile[r][c] = (cc < N_TRAIN) ? labels[(size_t)(r0 + r) * N_TRAIN + cc] : 0;
  }
  __syncthreads();
#pragma unroll
  for (int i = 0; i < 16; ++i) {
    int idx = i * 256 + t;
    int c = idx >> 6, r = idx & 63;
    int cc = c0 + c;
    if (cc < N_TRAIN) labT[(size_t)cc * 256 + r0 + r] = (unsigned char)tile[r][c];
  }
}

// ---------------- convert test [1568][384] f32 -> bf16A [1664][384] (pad 0) ---
__global__ __launch_bounds__(256) void conv_bf16A(const float* __restrict__ test,
                                                  unsigned short* __restrict__ bf16A) {
  int idx = blockIdx.x * 256 + threadIdx.x;      // over MPAD*DDIM = 638,976
  if (idx >= MPAD * DDIM) return;
  int row = idx / DDIM;
  bf16A[idx] = (row < M_ROWS) ? f2bf(test[idx]) : (unsigned short)0;
}

// -- fused transpose train [384][50000] f32 -> bhT bf16 [50176][384] + trainT f32
__global__ __launch_bounds__(256) void trans_train_fused(const float* __restrict__ train,
                                                         unsigned short* __restrict__ bhT,
                                                         float* __restrict__ trainT) {
  __shared__ float tile[64][65];
  const int t  = threadIdx.x;
  const int c0 = blockIdx.x * 64;   // col (0..50176)
  const int r0 = blockIdx.y * 64;   // k
#pragma unroll
  for (int i = 0; i < 16; ++i) {
    int idx = i * 256 + t;
    int r = idx >> 6, c = idx & 63;
    int cc = c0 + c;
    tile[r][c] = (cc < N_TRAIN) ? train[(size_t)(r0 + r) * N_TRAIN + cc] : 0.f;
  }
  __syncthreads();
#pragma unroll
  for (int i = 0; i < 16; ++i) {
    int idx = i * 256 + t;
    int c = idx >> 6, r = idx & 63;
    int cc = c0 + c;                 // < 50176 by grid construction
    float v = tile[r][c];
    bhT[(size_t)cc * DDIM + r0 + r] = f2bf(v);
    if (cc < N_TRAIN) trainT[(size_t)cc * DDIM + r0 + r] = v;
  }
}

// ---------------- MFMA bf16 GEMM: keys + per-block row-max --------------------
// 128x128 tile, 4 waves 2x2 (wave 64x64), BK=64. Both operands K-major bf16,
// staged with global_load_lds(16B) into linear LDS with pre-swizzled source.
// Epilogue: swizzled u16 C-tile in (reused) LDS -> coalesced dwordx4 stores.
__global__ __launch_bounds__(256) void mfma_gemm(const unsigned short* __restrict__ bf16A,
                                                 const unsigned short* __restrict__ bhT,
                                                 unsigned short* __restrict__ keybuf,
                                                 unsigned short* __restrict__ blkmax) {
  __shared__ unsigned short lds[16384];   // A:[0,8192) B:[8192,16384); epilogue C-tile
  const int t = threadIdx.x;

  // bijective XCD-chunked swizzle: 5096 = 8 * 637; same-n m-blocks -> same XCD
  const int flat = blockIdx.x;
  const int wrk  = (flat & 7) * 637 + (flat >> 3);
  const int nblk = wrk / 13, mblk = wrk % 13;
  const int m0 = mblk * 128, n0 = nblk * 128;

  const int wid = t >> 6, lane = t & 63;
  const int wr = wid >> 1, wc = wid & 1;
  const int l15 = lane & 15, l4 = lane >> 4;
  const int srow  = lane >> 3;                  // row-in-segment 0..7
  const int sslot = (lane & 7) ^ srow;          // pre-swizzled source k-slot

  f32x4 acc[4][4];
  const f32x4 zero = {0.f, 0.f, 0.f, 0.f};
#pragma unroll
  for (int f = 0; f < 4; ++f)
#pragma unroll
    for (int n = 0; n < 4; ++n) acc[f][n] = zero;

  for (int ks = 0; ks < DDIM / 64; ++ks) {
    __syncthreads();   // previous LDS reads done
#pragma unroll
    for (int j = 0; j < 4; ++j) {
      int seg  = wid * 4 + j;                    // 16 segments of 1024 B
      int arow = seg * 8 + srow;
      GLOAD_LDS16(bf16A + (size_t)(m0 + arow) * DDIM + ks * 64 + sslot * 8,
                  &lds[seg * 512]);
      GLOAD_LDS16(bhT + (size_t)(n0 + arow) * DDIM + ks * 64 + sslot * 8,
                  &lds[8192 + seg * 512]);
    }
    __syncthreads();   // compiler drains vmcnt before barrier
#pragma unroll
    for (int k2 = 0; k2 < 2; ++k2) {
      bf16x8 a[4], b[4];
#pragma unroll
      for (int f = 0; f < 4; ++f) {
        int row = wr * 64 + f * 16 + l15;
        int kel = (k2 * 32 + l4 * 8) ^ ((row & 7) << 3);
        a[f] = *(bf16x8*)&lds[row * 64 + kel];
      }
#pragma unroll
      for (int n = 0; n < 4; ++n) {
        int row = wc * 64 + n * 16 + l15;
        int kel = (k2 * 32 + l4 * 8) ^ ((row & 7) << 3);
        b[n] = *(bf16x8*)&lds[8192 + row * 64 + kel];
      }
#pragma unroll
      for (int f = 0; f < 4; ++f)
#pragma unroll
        for (int n = 0; n < 4; ++n)
          acc[f][n] = __builtin_amdgcn_mfma_f32_16x16x32_bf16(a[f], b[n], acc[f][n], 0, 0, 0);
    }
  }

  // ---- epilogue: swizzled u16 C-tile in LDS ----
  __syncthreads();   // all waves done reading A/B before overwrite
#pragma unroll
  for (int f = 0; f < 4; ++f) {
#pragma unroll
    for (int n = 0; n < 4; ++n) {
      const int col = wc * 64 + n * 16 + l15;
#pragma unroll
      for (int r = 0; r < 4; ++r) {
        const int row = wr * 64 + f * 16 + l4 * 4 + r;
        unsigned int k16 = flip32(__float_as_uint(acc[f][n][r])) >> 16;
        lds[row * 128 + (col ^ ((row & 15) << 3))] = (unsigned short)k16;
      }
    }
  }
  __syncthreads();

  // ---- coalesced readout: 8 x dwordx4 per thread + per-row blkmax ----
  const bool boundary = (n0 + 128 > N_TRAIN);
#pragma unroll
  for (int i = 0; i < 8; ++i) {
    int idx = i * 256 + t;                 // 0..2047
    int row = idx >> 4;                    // 0..127
    int c8  = (idx & 15) * 8;              // col group base
    uint4 v = *(uint4*)&lds[row * 128 + (c8 ^ ((row & 15) << 3))];
    if (boundary) {
      int nv = N_TRAIN - (n0 + c8);        // valid halves: j < nv
      v.x &= ((0 < nv) ? 0x0000FFFFu : 0u) | ((1 < nv) ? 0xFFFF0000u : 0u);
      v.y &= ((2 < nv) ? 0x0000FFFFu : 0u) | ((3 < nv) ? 0xFFFF0000u : 0u);
      v.z &= ((4 < nv) ? 0x0000FFFFu : 0u) | ((5 < nv) ? 0xFFFF0000u : 0u);
      v.w &= ((6 < nv) ? 0x0000FFFFu : 0u) | ((7 < nv) ? 0xFFFF0000u : 0u);
    }
    unsigned int mx = v.x & 0xFFFFu;
    mx = max(mx, v.x >> 16); mx = max(mx, v.y & 0xFFFFu); mx = max(mx, v.y >> 16);
    mx = max(mx, v.z & 0xFFFFu); mx = max(mx, v.z >> 16);
    mx = max(mx, v.w & 0xFFFFu); mx = max(mx, v.w >> 16);
    mx = max(mx, (unsigned int)__shfl_xor((int)mx, 1));
    mx = max(mx, (unsigned int)__shfl_xor((int)mx, 2));
    mx = max(mx, (unsigned int)__shfl_xor((int)mx, 4));
    mx = max(mx, (unsigned int)__shfl_xor((int)mx, 8));
    if ((lane & 15) == 0) blkmax[(size_t)(m0 + row) * NBLK + nblk] = (unsigned short)mx;
    if (m0 + row < M_ROWS)
      *(uint4*)&keybuf[(size_t)(m0 + row) * NPAD + n0 + c8] = v;
  }
}

// ---------------- exact candidate selection from block-maxes ------------------
__global__ __launch_bounds__(256) void select_all(const unsigned short* __restrict__ keybuf,
                                                  const unsigned short* __restrict__ blkmax,
                                                  int* __restrict__ selCols,
                                                  int* __restrict__ selCnt) {
  const int t = threadIdx.x, m = blockIdx.x;
  __shared__ unsigned short bm[NBLK];
  __shared__ int clist[CBMAX];
  __shared__ int ccnt;
  __shared__ unsigned int smax[256];
  __shared__ unsigned int sbuf[CAPBUF];
  __shared__ short srk[CAPBUF];
  __shared__ unsigned int scnt, sTauA, sTau;
  __shared__ int sC2;

  if (t == 0) { ccnt = 0; scnt = 0u; sC2 = 0; }
  for (int i = t; i < NBLK; i += 256) bm[i] = blkmax[(size_t)m * NBLK + i];
  __syncthreads();

  // candidate blocks: strict-greater-rank < K2 (includes all ties: superset)
  for (int i = t; i < NBLK; i += 256) {
    unsigned short v = bm[i];
    int cgt = 0;
    for (int j = 0; j < NBLK; ++j) cgt += (bm[j] > v) ? 1 : 0;
    if (cgt < K2) { int p = atomicAdd(&ccnt, 1); if (p < CBMAX) clist[p] = i; }
  }
  __syncthreads();
  const int CB = min(ccnt, CBMAX);
  const int TOT = CB * 128;

  // per-thread max over candidate-block keys
  unsigned int tmx = 0u;
  for (int i = t; i < TOT; i += 256) {
    int col = clist[i >> 7] * 128 + (i & 127);
    unsigned int k = keybuf[(size_t)m * NPAD + col];
    if (k > tmx) tmx = k;
  }
  smax[t] = (tmx << 8) | (unsigned int)(255 - t);
  __syncthreads();
  {
    unsigned int myc = smax[t];
    int rnk = 0;
    for (int j = 0; j < 256; ++j) rnk += (smax[j] > myc) ? 1 : 0;
    if (rnk == K2 - 1) sTauA = myc >> 8;
  }
  __syncthreads();
  const unsigned int tauB = sTauA;

  // collect all candidate keys >= tauB (guaranteed superset of exact top-24)
  for (int i = t; i < TOT; i += 256) {
    int col = clist[i >> 7] * 128 + (i & 127);
    unsigned int k = keybuf[(size_t)m * NPAD + col];
    if (k >= tauB) {
      unsigned int p = atomicAdd(&scnt, 1u);
      if (p < CAPBUF) sbuf[p] = (k << 16) | (unsigned int)(0xFFFF - col);
    }
  }
  __syncthreads();
  const int C = (int)min(scnt, (unsigned int)CAPBUF);

  for (int s = t; s < C; s += 256) {
    unsigned int e = sbuf[s];
    int rk = 0;
    for (int j = 0; j < C; ++j) rk += (sbuf[j] > e) ? 1 : 0;
    srk[s] = (short)rk;
    if (rk == K2 - 1) sTau = e >> 16;
  }
  __syncthreads();
  const unsigned int tau = sTau;
  for (int s = t; s < C; s += 256) {
    unsigned int e = sbuf[s];
    int rk = (int)srk[s];
    if ((e >> 16) >= tau && rk < SELMAX) {
      selCols[(size_t)m * SELMAX + rk] = 0xFFFF - (int)(e & 0xFFFFu);
      atomicMax(&sC2, rk + 1);
    }
  }
  __syncthreads();
  if (t == 0) selCnt[m] = sC2 < SELMAX ? sC2 : SELMAX;
}

// ---------------- f64 refine of <=64 cands -> exact top-20 -> f64 softmax -----
__global__ __launch_bounds__(256) void refine_softmax(const int* __restrict__ selCols,
                                                      const int* __restrict__ selCnt,
                                                      const float* __restrict__ test,
                                                      const float* __restrict__ trainT,
                                                      double* __restrict__ wval,
                                                      int* __restrict__ widx) {
  const int m = blockIdx.x, t = threadIdx.x;
  __shared__ int    sIdx[SELMAX];
  __shared__ double rvs[SELMAX];
  __shared__ double sv2[SELMAX];
  __shared__ int    si2[SELMAX];
  __shared__ double earr[KNN];
  const int C2 = selCnt[m];                 // 24 <= C2 <= 64
  if (t < C2) sIdx[t] = selCols[(size_t)m * SELMAX + t];
  __syncthreads();

  const int wid = t >> 6, lane = t & 63;
  float tr[DDIM / 64];
#pragma unroll
  for (int dd = 0; dd < DDIM / 64; ++dd)
    tr[dd] = test[(size_t)m * DDIM + dd * 64 + lane];
#pragma unroll 1
  for (int c = wid; c < C2; c += 4) {
    const float* Tc = trainT + (size_t)sIdx[c] * DDIM;
    double s = 0.0;
#pragma unroll
    for (int dd = 0; dd < DDIM / 64; ++dd)
      s += (double)tr[dd] * (double)Tc[dd * 64 + lane];
#pragma unroll
    for (int off = 32; off > 0; off >>= 1) s += __shfl_xor(s, off);
    if (lane == 0) rvs[c] = s;
  }
  __syncthreads();

  if (t < C2) {
    double v = rvs[t]; int id = sIdx[t];
    int r = 0;
    for (int n = 0; n < C2; ++n)
      r += (rvs[n] > v || (rvs[n] == v && sIdx[n] < id)) ? 1 : 0;
    sv2[r] = v; si2[r] = id;
  }
  __syncthreads();

  if (t < KNN) earr[t] = exp(sv2[t] - sv2[0]);
  __syncthreads();
  if (t < KNN) {
    double ssum = 0.0;
    for (int k = 0; k < KNN; ++k) ssum += earr[k];
    wval[(size_t)m * KNN + t] = earr[t] / ssum;
    widx[(size_t)m * KNN + t] = si2[t];
  }
}

// ---------------- per-pixel weighted vote (f64) + argmax ----------------------
__global__ __launch_bounds__(256) void vote_kernel(const double* __restrict__ wval,
                                                   const int* __restrict__ widx,
                                                   const unsigned char* __restrict__ labT,
                                                   int* __restrict__ out) {
  const int m = blockIdx.x, t = threadIdx.x;
  __shared__ double sw[KNN];
  __shared__ int    si[KNN];
  if (t < KNN) { sw[t] = wval[(size_t)m * KNN + t]; si[t] = widx[(size_t)m * KNN + t]; }
  __syncthreads();

  unsigned int packed[5];
#pragma unroll
  for (int q = 0; q < 5; ++q) {
    unsigned int p = 0;
#pragma unroll
    for (int j = 0; j < 4; ++j)
      p |= (unsigned int)labT[(size_t)si[q * 4 + j] * 256 + t] << (8 * j);
    packed[q] = p;
  }

  double best = -1.0; int bc = 0;
#pragma unroll 1
  for (int c = 0; c < NCLS; ++c) {
    double s = 0.0;
#pragma unroll
    for (int k = 0; k < KNN; ++k) {
      unsigned int lab = (packed[k >> 2] >> ((k & 3) * 8)) & 255u;
      s += (lab == (unsigned int)c) ? sw[k] : 0.0;
    }
    if (s > best) { best = s; bc = c; }
  }

  const int b = m / 196, p = m % 196;
  const int py = p / 14, px = p % 14;
  const int i = t >> 4, j = t & 15;
  out[((size_t)b * 224 + py * 16 + i) * 224 + px * 16 + j] = bc;
}

// ---------------- launch ------------------------------------------------------
// ws layout (bytes), total 288,853,632 (< ~307 MB poisoned ws; NO aliasing):
//   labT    @ 0           : 12,800,000
//   bf16A   @ 12,800,000  :  1,277,952  (u16 [1664][384])
//   bhT     @ 14,077,952  : 38,535,168  (u16 [50176][384])
//   keybuf  @ 52,613,120  : 157,351,936 (u16 [1568][50176])
//   trainT  @ 209,965,056 : 76,800,000  (f32 [50000][384])
//   blkmax  @ 286,765,056 :  1,304,576  (u16 [1664][392])
//   selCols @ 288,069,632 :    401,408
//   selCnt  @ 288,471,040 :      6,272
//   wval    @ 288,477,312 :    250,880
//   widx    @ 288,728,192 :    125,440
extern "C" void kernel_launch(void* const* d_in, const int* in_sizes, int n_in,
                              void* d_out, int out_size, void* d_ws, size_t ws_size,
                              hipStream_t stream) {
  const float* test  = (const float*)d_in[0];   // [1568][384]
  const float* train = (const float*)d_in[1];   // [384][50000]
  const int* labels  = (const int*)d_in[2];     // [256][50000]
  int* out = (int*)d_out;
  char* ws = (char*)d_ws;

  unsigned char*  labT    = (unsigned char*)ws;
  unsigned short* bf16A   = (unsigned short*)(ws + 12800000);
  unsigned short* bhT     = (unsigned short*)(ws + 14077952);
  unsigned short* keybuf  = (unsigned short*)(ws + 52613120);
  float*          trainT  = (float*)(ws + 209965056);
  unsigned short* blkmax  = (unsigned short*)(ws + 286765056);
  int*            selCols = (int*)(ws + 288069632);
  int*            selCnt  = (int*)(ws + 288471040);
  double*         wval    = (double*)(ws + 288477312);
  int*            widx    = (int*)(ws + 288728192);

  transpose_labels<<<dim3(782, 4), 256, 0, stream>>>(labels, labT);
  conv_bf16A<<<dim3((MPAD * DDIM + 255) / 256), 256, 0, stream>>>(test, bf16A);
  trans_train_fused<<<dim3(784, 6), 256, 0, stream>>>(train, bhT, trainT);
  mfma_gemm<<<dim3(13 * NBLK), 256, 0, stream>>>(bf16A, bhT, keybuf, blkmax);
  select_all<<<dim3(M_ROWS), 256, 0, stream>>>(keybuf, blkmax, selCols, selCnt);
  refine_softmax<<<dim3(M_ROWS), 256, 0, stream>>>(selCols, selCnt, test, trainT, wval, widx);
  vote_kernel<<<dim3(M_ROWS), 256, 0, stream>>>(wval, widx, labT, out);
}